// Round 1
// baseline (2495.711 us; speedup 1.0000x reference)
//
#include <hip/hip_runtime.h>
#include <hip/hip_bf16.h>
#include <math.h>

// Problem constants (from reference)
#define B_    4
#define T_    512
#define BT    2048      // B*T rows
#define STOCH 1024
#define DM    512       // d_model
#define DI    1024      // d_inner
#define DS    16        // d_state
#define DTR   32        // dt_rank
#define KC    4         // conv kernel
#define NL    4         // layers
#define EPSV  1e-5f

// ---------------------------------------------------------------------------
// Generic fp32 tiled GEMM: C[M,N] = A[M,K] @ Bw[K,N]  (+ epilogue)
// 64x64 tile, 256 threads (16x16), 4x4 per thread, K-tile 16.
// EP=0: plain   EP=1: + b_embed[n] + act_embed[act[m]][n]
// EP=2: softplus(c + e1[n])       EP=3: + e1[m*ldc+n] (residual)
// ---------------------------------------------------------------------------
template<int EP>
__global__ __launch_bounds__(256)
void gemm64(const float* __restrict__ A, int lda,
            const float* __restrict__ Bw, int ldb,
            float* __restrict__ C, int ldc,
            int M, int N, int Kd,
            const float* __restrict__ e1,
            const float* __restrict__ e2,
            const int* __restrict__ act)
{
    __shared__ float As[16][68];
    __shared__ float Bs[16][68];
    const int tx = threadIdx.x;            // 0..15 -> n
    const int ty = threadIdx.y;            // 0..15 -> m
    const int tid = ty * 16 + tx;
    const int bm = blockIdx.y * 64;
    const int bn = blockIdx.x * 64;

    float c[4][4] = {};

    for (int k0 = 0; k0 < Kd; k0 += 16) {
        // A tile: As[kk][mloc] = A[(bm+mloc)*lda + k0+kk]
        #pragma unroll
        for (int j = 0; j < 4; j++) {
            int idx = tid + 256 * j;
            int kk = idx & 15, ml = idx >> 4;
            As[kk][ml] = A[(size_t)(bm + ml) * lda + k0 + kk];
        }
        // B tile: Bs[kk][nloc] = Bw[(k0+kk)*ldb + bn+nloc]
        #pragma unroll
        for (int j = 0; j < 4; j++) {
            int idx = tid + 256 * j;
            int nl = idx & 63, kk = idx >> 6;
            Bs[kk][nl] = Bw[(size_t)(k0 + kk) * ldb + bn + nl];
        }
        __syncthreads();
        #pragma unroll
        for (int kk = 0; kk < 16; kk++) {
            float a[4], b[4];
            #pragma unroll
            for (int i = 0; i < 4; i++) a[i] = As[kk][ty * 4 + i];
            #pragma unroll
            for (int i = 0; i < 4; i++) b[i] = Bs[kk][tx * 4 + i];
            #pragma unroll
            for (int i = 0; i < 4; i++)
                #pragma unroll
                for (int j = 0; j < 4; j++)
                    c[i][j] += a[i] * b[j];
        }
        __syncthreads();
    }

    #pragma unroll
    for (int i = 0; i < 4; i++) {
        int m = bm + ty * 4 + i;
        #pragma unroll
        for (int j = 0; j < 4; j++) {
            int n = bn + tx * 4 + j;
            float v = c[i][j];
            if (EP == 1) v += e1[n] + e2[(size_t)act[m] * DM + n];
            if (EP == 2) { v += e1[n]; v = fmaxf(v, 0.f) + log1pf(expf(-fabsf(v))); }
            if (EP == 3) v += e1[(size_t)m * ldc + n];
            C[(size_t)m * ldc + n] = v;
        }
    }
}

// ---------------------------------------------------------------------------
// LayerNorm over rows of length DM. grid = rows, block = 256.
// ---------------------------------------------------------------------------
__global__ __launch_bounds__(256)
void ln_kernel(const float* __restrict__ x, const float* __restrict__ w,
               const float* __restrict__ bb, float* __restrict__ o)
{
    const int row = blockIdx.x;
    const int tid = threadIdx.x;
    const float* xr = x + (size_t)row * DM;
    float s = 0.f, ss = 0.f;
    for (int i = tid; i < DM; i += 256) { float v = xr[i]; s += v; ss += v * v; }
    #pragma unroll
    for (int m = 32; m >= 1; m >>= 1) { s += __shfl_xor(s, m, 64); ss += __shfl_xor(ss, m, 64); }
    __shared__ float sm[4], sm2[4];
    const int wv = tid >> 6;
    if ((tid & 63) == 0) { sm[wv] = s; sm2[wv] = ss; }
    __syncthreads();
    s  = sm[0] + sm[1] + sm[2] + sm[3];
    ss = sm2[0] + sm2[1] + sm2[2] + sm2[3];
    const float mean = s * (1.f / DM);
    float var = ss * (1.f / DM) - mean * mean;
    var = fmaxf(var, 0.f);
    const float rstd = rsqrtf(var + EPSV);
    for (int i = tid; i < DM; i += 256) {
        float v = (xr[i] - mean) * rstd;
        o[(size_t)row * DM + i] = v * w[i] + bb[i];
    }
}

// ---------------------------------------------------------------------------
// Causal depthwise conv (K=4) + SiLU.  xin = xz[:, :DI] (row stride 2048).
// One thread per (bt, d) element.
// ---------------------------------------------------------------------------
__global__ __launch_bounds__(256)
void conv_silu(const float* __restrict__ xz, const float* __restrict__ cw,
               const float* __restrict__ cb, float* __restrict__ xc)
{
    const int idx = blockIdx.x * 256 + threadIdx.x;   // over BT*DI
    const int d = idx & (DI - 1);
    const int bt = idx >> 10;
    const int t = bt & (T_ - 1);
    float acc = cb[d];
    #pragma unroll
    for (int k = 0; k < KC; k++) {
        int sh = 3 - k;                       // how far back in time
        if (t >= sh) acc += cw[d * KC + k] * xz[(size_t)(bt - sh) * 2048 + d];
    }
    const float sg = 1.f / (1.f + expf(-acc));
    xc[idx] = acc * sg;
}

// ---------------------------------------------------------------------------
// Selective scan. grid = B * DI/16 blocks; block 256 = 16 d-channels x 16 states.
// tid: s = tid&15 (state), dl = tid>>4 (local channel).
// Fuses y = (scan + D*xc) * silu(z) epilogue.
// ---------------------------------------------------------------------------
__global__ __launch_bounds__(256)
void scan_kernel(const float* __restrict__ dt, const float* __restrict__ xc,
                 const float* __restrict__ dbc, const float* __restrict__ xz,
                 const float* __restrict__ A_log, const float* __restrict__ Dskip,
                 float* __restrict__ y)
{
    const int blk = blockIdx.x;
    const int b = blk >> 6;                 // DI/16 = 64 chunks per batch
    const int d0 = (blk & 63) * 16;
    const int tid = threadIdx.x;
    const int s = tid & 15;
    const int dl = tid >> 4;
    const int d = d0 + dl;

    const float Aval = -expf(A_log[(size_t)d * DS + s]);
    const float Dv = Dskip[d];
    float h = 0.f;
    const size_t base = (size_t)b * T_;

    for (int t = 0; t < T_; t++) {
        const size_t r = base + t;
        const float dtv = dt[r * DI + d];
        const float xv  = xc[r * DI + d];
        const float Bv  = dbc[r * 64 + 32 + s];
        const float Cv  = dbc[r * 64 + 48 + s];
        const float dA = expf(dtv * Aval);
        h = dA * h + (dtv * xv) * Bv;
        float p = h * Cv;
        p += __shfl_xor(p, 1, 16);
        p += __shfl_xor(p, 2, 16);
        p += __shfl_xor(p, 4, 16);
        p += __shfl_xor(p, 8, 16);
        if (s == 0) {
            const float zv = xz[r * 2048 + 1024 + d];
            const float sg = 1.f / (1.f + expf(-zv));
            y[r * DI + d] = (p + Dv * xv) * (zv * sg);
        }
    }
}

// ---------------------------------------------------------------------------
// Mean over T: out[b,d] = mean_t x[b,t,d]
// ---------------------------------------------------------------------------
__global__ __launch_bounds__(256)
void mean_kernel(const float* __restrict__ x, float* __restrict__ out)
{
    const int idx = blockIdx.x * 256 + threadIdx.x;   // B*DM
    const int b = idx / DM;
    const int dcol = idx % DM;
    float ssum = 0.f;
    for (int t = 0; t < T_; t++) ssum += x[((size_t)b * T_ + t) * DM + dcol];
    out[idx] = ssum * (1.f / T_);
}

// ---------------------------------------------------------------------------
extern "C" void kernel_launch(void* const* d_in, const int* in_sizes, int n_in,
                              void* d_out, int out_size, void* d_ws, size_t ws_size,
                              hipStream_t stream)
{
    const float* samples  = (const float*)d_in[0];
    const int*   actions  = (const int*)  d_in[1];
    const float* W_embed  = (const float*)d_in[2];
    const float* b_embed  = (const float*)d_in[3];
    const float* act_emb  = (const float*)d_in[4];
    const float* ln_w     = (const float*)d_in[5];
    const float* ln_b     = (const float*)d_in[6];
    const float* W_in     = (const float*)d_in[7];
    const float* conv_w   = (const float*)d_in[8];
    const float* conv_b   = (const float*)d_in[9];
    const float* W_xproj  = (const float*)d_in[10];
    const float* W_dt     = (const float*)d_in[11];
    const float* b_dt     = (const float*)d_in[12];
    const float* A_log    = (const float*)d_in[13];
    const float* D_skip   = (const float*)d_in[14];
    const float* W_out    = (const float*)d_in[15];
    const float* normf_w  = (const float*)d_in[16];
    const float* normf_b  = (const float*)d_in[17];
    const float* out_ln_w = (const float*)d_in[18];
    const float* out_ln_b = (const float*)d_in[19];

    float* ws  = (float*)d_ws;
    float* x   = ws;                         // BT*DM
    float* h   = x   + (size_t)BT * DM;      // BT*DM
    float* xz  = h   + (size_t)BT * DM;      // BT*2048
    float* xc  = xz  + (size_t)BT * 2048;    // BT*DI
    float* dbc = xc  + (size_t)BT * DI;      // BT*64
    float* dtb = dbc + (size_t)BT * 64;      // BT*DI
    float* yg  = dtb + (size_t)BT * DI;      // BT*DI

    dim3 blk(16, 16);

    // x = samples @ W_embed + b_embed + act_embed[actions]
    gemm64<1><<<dim3(DM / 64, BT / 64), blk, 0, stream>>>(
        samples, STOCH, W_embed, DM, x, DM, BT, DM, STOCH, b_embed, act_emb, actions);

    for (int l = 0; l < NL; l++) {
        // h = LN(x)
        ln_kernel<<<BT, 256, 0, stream>>>(x, ln_w + l * DM, ln_b + l * DM, h);
        // xz = h @ W_in[l]
        gemm64<0><<<dim3(2048 / 64, BT / 64), blk, 0, stream>>>(
            h, DM, W_in + (size_t)l * DM * 2048, 2048, xz, 2048, BT, 2048, DM,
            nullptr, nullptr, nullptr);
        // xc = silu(causal depthwise conv(xin) + conv_b)
        conv_silu<<<(BT * DI) / 256, 256, 0, stream>>>(
            xz, conv_w + (size_t)l * DI * KC, conv_b + (size_t)l * DI, xc);
        // dbc = xc @ W_xproj[l]
        gemm64<0><<<dim3(64 / 64, BT / 64), blk, 0, stream>>>(
            xc, DI, W_xproj + (size_t)l * DI * 64, 64, dbc, 64, BT, 64, DI,
            nullptr, nullptr, nullptr);
        // dt = softplus(dbc[:, :32] @ W_dt[l] + b_dt[l])
        gemm64<2><<<dim3(DI / 64, BT / 64), blk, 0, stream>>>(
            dbc, 64, W_dt + (size_t)l * DTR * DI, DI, dtb, DI, BT, DI, DTR,
            b_dt + (size_t)l * DI, nullptr, nullptr);
        // selective scan + D-skip + silu(z) gating
        scan_kernel<<<B_ * (DI / 16), 256, 0, stream>>>(
            dtb, xc, dbc, xz, A_log + (size_t)l * DI * DS, D_skip + (size_t)l * DI, yg);
        // x = x + yg @ W_out[l]
        gemm64<3><<<dim3(DM / 64, BT / 64), blk, 0, stream>>>(
            yg, DI, W_out + (size_t)l * DI * DM, DM, x, DM, BT, DM, DI,
            x, nullptr, nullptr);
    }

    // final LN x2, then mean over T
    ln_kernel<<<BT, 256, 0, stream>>>(x, normf_w, normf_b, h);
    ln_kernel<<<BT, 256, 0, stream>>>(h, out_ln_w, out_ln_b, yg);
    mean_kernel<<<(B_ * DM) / 256, 256, 0, stream>>>(yg, (float*)d_out);
}

// Round 2
// 1287.331 us; speedup vs baseline: 1.9387x; 1.9387x over previous
//
#include <hip/hip_runtime.h>
#include <hip/hip_bf16.h>
#include <math.h>

// Problem constants (from reference)
#define B_    4
#define T_    512
#define BT    2048      // B*T rows
#define STOCH 1024
#define DM    512       // d_model
#define DI    1024      // d_inner
#define DS    16        // d_state
#define DTR   32        // dt_rank
#define KC    4         // conv kernel
#define NL    4         // layers
#define EPSV  1e-5f
#define CH    16        // scan chunks
#define TC    32        // T_/CH steps per chunk

// ---------------------------------------------------------------------------
// Generic fp32 tiled GEMM: C[M,N] = A[M,K] @ Bw[K,N]  (+ epilogue)
// 64x64 tile, 256 threads (16x16), 4x4 per thread, K-tile 16.
// EP=0: plain   EP=1: + b_embed[n] + act_embed[act[m]][n]
// EP=2: softplus(c + e1[n])       EP=3: + e1[m*ldc+n] (residual)
// ---------------------------------------------------------------------------
template<int EP>
__global__ __launch_bounds__(256)
void gemm64(const float* __restrict__ A, int lda,
            const float* __restrict__ Bw, int ldb,
            float* __restrict__ C, int ldc,
            int M, int N, int Kd,
            const float* __restrict__ e1,
            const float* __restrict__ e2,
            const int* __restrict__ act)
{
    __shared__ float As[16][68];
    __shared__ float Bs[16][68];
    const int tx = threadIdx.x;            // 0..15 -> n
    const int ty = threadIdx.y;            // 0..15 -> m
    const int tid = ty * 16 + tx;
    const int bm = blockIdx.y * 64;
    const int bn = blockIdx.x * 64;

    float c[4][4] = {};

    for (int k0 = 0; k0 < Kd; k0 += 16) {
        #pragma unroll
        for (int j = 0; j < 4; j++) {
            int idx = tid + 256 * j;
            int kk = idx & 15, ml = idx >> 4;
            As[kk][ml] = A[(size_t)(bm + ml) * lda + k0 + kk];
        }
        #pragma unroll
        for (int j = 0; j < 4; j++) {
            int idx = tid + 256 * j;
            int nl = idx & 63, kk = idx >> 6;
            Bs[kk][nl] = Bw[(size_t)(k0 + kk) * ldb + bn + nl];
        }
        __syncthreads();
        #pragma unroll
        for (int kk = 0; kk < 16; kk++) {
            float a[4], b[4];
            #pragma unroll
            for (int i = 0; i < 4; i++) a[i] = As[kk][ty * 4 + i];
            #pragma unroll
            for (int i = 0; i < 4; i++) b[i] = Bs[kk][tx * 4 + i];
            #pragma unroll
            for (int i = 0; i < 4; i++)
                #pragma unroll
                for (int j = 0; j < 4; j++)
                    c[i][j] += a[i] * b[j];
        }
        __syncthreads();
    }

    #pragma unroll
    for (int i = 0; i < 4; i++) {
        int m = bm + ty * 4 + i;
        #pragma unroll
        for (int j = 0; j < 4; j++) {
            int n = bn + tx * 4 + j;
            float v = c[i][j];
            if (EP == 1) v += e1[n] + e2[(size_t)act[m] * DM + n];
            if (EP == 2) { v += e1[n]; v = fmaxf(v, 0.f) + log1pf(expf(-fabsf(v))); }
            if (EP == 3) v += e1[(size_t)m * ldc + n];
            C[(size_t)m * ldc + n] = v;
        }
    }
}

// ---------------------------------------------------------------------------
// LayerNorm over rows of length DM. grid = rows, block = 256.
// ---------------------------------------------------------------------------
__global__ __launch_bounds__(256)
void ln_kernel(const float* __restrict__ x, const float* __restrict__ w,
               const float* __restrict__ bb, float* __restrict__ o)
{
    const int row = blockIdx.x;
    const int tid = threadIdx.x;
    const float* xr = x + (size_t)row * DM;
    float s = 0.f, ss = 0.f;
    for (int i = tid; i < DM; i += 256) { float v = xr[i]; s += v; ss += v * v; }
    #pragma unroll
    for (int m = 32; m >= 1; m >>= 1) { s += __shfl_xor(s, m, 64); ss += __shfl_xor(ss, m, 64); }
    __shared__ float sm[4], sm2[4];
    const int wv = tid >> 6;
    if ((tid & 63) == 0) { sm[wv] = s; sm2[wv] = ss; }
    __syncthreads();
    s  = sm[0] + sm[1] + sm[2] + sm[3];
    ss = sm2[0] + sm2[1] + sm2[2] + sm2[3];
    const float mean = s * (1.f / DM);
    float var = ss * (1.f / DM) - mean * mean;
    var = fmaxf(var, 0.f);
    const float rstd = rsqrtf(var + EPSV);
    for (int i = tid; i < DM; i += 256) {
        float v = (xr[i] - mean) * rstd;
        o[(size_t)row * DM + i] = v * w[i] + bb[i];
    }
}

// ---------------------------------------------------------------------------
// Causal depthwise conv (K=4) + SiLU.  xin = xz[:, :DI] (row stride 2048).
// ---------------------------------------------------------------------------
__global__ __launch_bounds__(256)
void conv_silu(const float* __restrict__ xz, const float* __restrict__ cw,
               const float* __restrict__ cb, float* __restrict__ xc)
{
    const int idx = blockIdx.x * 256 + threadIdx.x;   // over BT*DI
    const int d = idx & (DI - 1);
    const int bt = idx >> 10;
    const int t = bt & (T_ - 1);
    float acc = cb[d];
    #pragma unroll
    for (int k = 0; k < KC; k++) {
        int sh = 3 - k;
        if (t >= sh) acc += cw[d * KC + k] * xz[(size_t)(bt - sh) * 2048 + d];
    }
    const float sg = 1.f / (1.f + expf(-acc));
    xc[idx] = acc * sg;
}

// ---------------------------------------------------------------------------
// Chunked selective scan, pass A: per-chunk local scan (h0 = 0).
// grid = B * (DI/16) * CH blocks; block 256 = 16 d-channels x 16 states.
// blk = ((b*64 + dg)*CH + c).  Stores Aprod (prod of dA) and hloc (final h).
// ---------------------------------------------------------------------------
__global__ __launch_bounds__(256)
void scan_passA(const float* __restrict__ dt, const float* __restrict__ xc,
                const float* __restrict__ dbc, const float* __restrict__ A_log,
                float* __restrict__ Aprod, float* __restrict__ hloc)
{
    const int blk = blockIdx.x;
    const int c  = blk & (CH - 1);
    const int dg = (blk >> 4) & 63;
    const int b  = blk >> 10;
    const int tid = threadIdx.x;
    const int s = tid & 15;
    const int dl = tid >> 4;
    const int d = dg * 16 + dl;

    const float Aval = -expf(A_log[(size_t)d * DS + s]);
    float h = 0.f, ap = 1.f;
    const size_t base = (size_t)b * T_ + c * TC;

    #pragma unroll 4
    for (int t = 0; t < TC; t++) {
        const size_t r = base + t;
        const float dtv = dt[r * DI + d];
        const float xv  = xc[r * DI + d];
        const float Bv  = dbc[r * 64 + 32 + s];
        const float a = expf(dtv * Aval);
        h = a * h + (dtv * xv) * Bv;
        ap *= a;
    }
    // layout: [b][c][DI*DS], contiguous per block: dg*256 + tid
    const size_t o = ((size_t)(b * CH + c) * DI) * DS + dg * 256 + tid;
    Aprod[o] = ap;
    hloc[o]  = h;
}

// ---------------------------------------------------------------------------
// Chunked selective scan, pass C: fold upstream chunk summaries to get h0,
// then recompute chunk emitting y = (h.C + D*xc) * silu(z).
// ---------------------------------------------------------------------------
__global__ __launch_bounds__(256)
void scan_passC(const float* __restrict__ dt, const float* __restrict__ xc,
                const float* __restrict__ dbc, const float* __restrict__ xz,
                const float* __restrict__ A_log, const float* __restrict__ Dskip,
                const float* __restrict__ Aprod, const float* __restrict__ hloc,
                float* __restrict__ y)
{
    const int blk = blockIdx.x;
    const int c  = blk & (CH - 1);
    const int dg = (blk >> 4) & 63;
    const int b  = blk >> 10;
    const int tid = threadIdx.x;
    const int s = tid & 15;
    const int dl = tid >> 4;
    const int d = dg * 16 + dl;

    // reconstruct h at chunk start from upstream summaries
    float h = 0.f;
    const size_t obase = (size_t)b * CH * DI * DS + dg * 256 + tid;
    for (int cc = 0; cc < c; cc++) {
        const size_t o = obase + (size_t)cc * DI * DS;
        h = Aprod[o] * h + hloc[o];
    }

    const float Aval = -expf(A_log[(size_t)d * DS + s]);
    const float Dv = Dskip[d];
    const size_t base = (size_t)b * T_ + c * TC;

    #pragma unroll 2
    for (int t = 0; t < TC; t++) {
        const size_t r = base + t;
        const float dtv = dt[r * DI + d];
        const float xv  = xc[r * DI + d];
        const float Bv  = dbc[r * 64 + 32 + s];
        const float Cv  = dbc[r * 64 + 48 + s];
        const float a = expf(dtv * Aval);
        h = a * h + (dtv * xv) * Bv;
        float p = h * Cv;
        p += __shfl_xor(p, 1, 16);
        p += __shfl_xor(p, 2, 16);
        p += __shfl_xor(p, 4, 16);
        p += __shfl_xor(p, 8, 16);
        if (s == 0) {
            const float zv = xz[r * 2048 + 1024 + d];
            const float sg = 1.f / (1.f + expf(-zv));
            y[r * DI + d] = (p + Dv * xv) * (zv * sg);
        }
    }
}

// ---------------------------------------------------------------------------
// Mean over T: out[b,d] = mean_t x[b,t,d]
// ---------------------------------------------------------------------------
__global__ __launch_bounds__(256)
void mean_kernel(const float* __restrict__ x, float* __restrict__ out)
{
    const int idx = blockIdx.x * 256 + threadIdx.x;   // B*DM
    const int b = idx / DM;
    const int dcol = idx % DM;
    float ssum = 0.f;
    for (int t = 0; t < T_; t++) ssum += x[((size_t)b * T_ + t) * DM + dcol];
    out[idx] = ssum * (1.f / T_);
}

// ---------------------------------------------------------------------------
extern "C" void kernel_launch(void* const* d_in, const int* in_sizes, int n_in,
                              void* d_out, int out_size, void* d_ws, size_t ws_size,
                              hipStream_t stream)
{
    const float* samples  = (const float*)d_in[0];
    const int*   actions  = (const int*)  d_in[1];
    const float* W_embed  = (const float*)d_in[2];
    const float* b_embed  = (const float*)d_in[3];
    const float* act_emb  = (const float*)d_in[4];
    const float* ln_w     = (const float*)d_in[5];
    const float* ln_b     = (const float*)d_in[6];
    const float* W_in     = (const float*)d_in[7];
    const float* conv_w   = (const float*)d_in[8];
    const float* conv_b   = (const float*)d_in[9];
    const float* W_xproj  = (const float*)d_in[10];
    const float* W_dt     = (const float*)d_in[11];
    const float* b_dt     = (const float*)d_in[12];
    const float* A_log    = (const float*)d_in[13];
    const float* D_skip   = (const float*)d_in[14];
    const float* W_out    = (const float*)d_in[15];
    const float* normf_w  = (const float*)d_in[16];
    const float* normf_b  = (const float*)d_in[17];
    const float* out_ln_w = (const float*)d_in[18];
    const float* out_ln_b = (const float*)d_in[19];

    float* ws  = (float*)d_ws;
    float* x    = ws;                          // BT*DM
    float* h    = x    + (size_t)BT * DM;      // BT*DM
    float* xz   = h    + (size_t)BT * DM;      // BT*2048
    float* xc   = xz   + (size_t)BT * 2048;    // BT*DI
    float* dbc  = xc   + (size_t)BT * DI;      // BT*64
    float* dtb  = dbc  + (size_t)BT * 64;      // BT*DI
    float* yg   = dtb  + (size_t)BT * DI;      // BT*DI
    float* Apr  = yg   + (size_t)BT * DI;      // B*CH*DI*DS
    float* hlo  = Apr  + (size_t)B_ * CH * DI * DS;  // B*CH*DI*DS

    dim3 blk(16, 16);

    gemm64<1><<<dim3(DM / 64, BT / 64), blk, 0, stream>>>(
        samples, STOCH, W_embed, DM, x, DM, BT, DM, STOCH, b_embed, act_emb, actions);

    for (int l = 0; l < NL; l++) {
        ln_kernel<<<BT, 256, 0, stream>>>(x, ln_w + l * DM, ln_b + l * DM, h);
        gemm64<0><<<dim3(2048 / 64, BT / 64), blk, 0, stream>>>(
            h, DM, W_in + (size_t)l * DM * 2048, 2048, xz, 2048, BT, 2048, DM,
            nullptr, nullptr, nullptr);
        conv_silu<<<(BT * DI) / 256, 256, 0, stream>>>(
            xz, conv_w + (size_t)l * DI * KC, conv_b + (size_t)l * DI, xc);
        gemm64<0><<<dim3(64 / 64, BT / 64), blk, 0, stream>>>(
            xc, DI, W_xproj + (size_t)l * DI * 64, 64, dbc, 64, BT, 64, DI,
            nullptr, nullptr, nullptr);
        gemm64<2><<<dim3(DI / 64, BT / 64), blk, 0, stream>>>(
            dbc, 64, W_dt + (size_t)l * DTR * DI, DI, dtb, DI, BT, DI, DTR,
            b_dt + (size_t)l * DI, nullptr, nullptr);
        scan_passA<<<B_ * (DI / 16) * CH, 256, 0, stream>>>(
            dtb, xc, dbc, A_log + (size_t)l * DI * DS, Apr, hlo);
        scan_passC<<<B_ * (DI / 16) * CH, 256, 0, stream>>>(
            dtb, xc, dbc, xz, A_log + (size_t)l * DI * DS, D_skip + (size_t)l * DI,
            Apr, hlo, yg);
        gemm64<3><<<dim3(DM / 64, BT / 64), blk, 0, stream>>>(
            yg, DI, W_out + (size_t)l * DI * DM, DM, x, DM, BT, DM, DI,
            x, nullptr, nullptr);
    }

    ln_kernel<<<BT, 256, 0, stream>>>(x, normf_w, normf_b, h);
    ln_kernel<<<BT, 256, 0, stream>>>(h, out_ln_w, out_ln_b, yg);
    mean_kernel<<<(B_ * DM) / 256, 256, 0, stream>>>(yg, (float*)d_out);
}

// Round 3
// 851.506 us; speedup vs baseline: 2.9309x; 1.5118x over previous
//
#include <hip/hip_runtime.h>
#include <hip/hip_bf16.h>
#include <math.h>

// Problem constants (from reference)
#define B_    4
#define T_    512
#define BT    2048      // B*T rows
#define STOCH 1024
#define DM    512       // d_model
#define DI    1024      // d_inner
#define DS    16        // d_state
#define DTR   32        // dt_rank
#define KC    4         // conv kernel
#define NL    4         // layers
#define EPSV  1e-5f
#define CH    16        // scan chunks
#define TC    32        // T_/CH steps per chunk
#define SK    16        // xproj split-K slices

typedef short bf16x8 __attribute__((ext_vector_type(8)));
typedef float f32x4  __attribute__((ext_vector_type(4)));

__device__ __forceinline__ ushort bfbits(float f) {
    uint u = __float_as_uint(f);
    u += 0x7FFFu + ((u >> 16) & 1u);       // RTNE (no NaN handling needed here)
    return (ushort)(u >> 16);
}

// ---------------------------------------------------------------------------
// Batched weight convert+transpose: W[K][N] fp32 -> Wt[N][K] bf16.
// grid (N/32, K/32, batch), block (32, 8). LDS 32x33 tile, both sides coalesced.
// ---------------------------------------------------------------------------
__global__ __launch_bounds__(256)
void wconvT(const float* __restrict__ W, short* __restrict__ Wt, int K, int N)
{
    const float* Wb = W + (size_t)blockIdx.z * K * N;
    short* Wtb = Wt + (size_t)blockIdx.z * K * N;
    __shared__ float tile[32][33];
    const int tx = threadIdx.x, ty = threadIdx.y;
    const int n0 = blockIdx.x * 32, k0 = blockIdx.y * 32;
    #pragma unroll
    for (int j = 0; j < 4; j++)
        tile[ty + j * 8][tx] = Wb[(size_t)(k0 + ty + j * 8) * N + n0 + tx];
    __syncthreads();
    #pragma unroll
    for (int j = 0; j < 4; j++) {
        const int n = ty + j * 8;
        Wtb[(size_t)(n0 + n) * K + k0 + tx] = (short)bfbits(tile[tx][n]);
    }
}

// ---------------------------------------------------------------------------
// bf16 MFMA GEMM: C[M,N](f32) = A[M,K](f32, converted on the fly) @ Wt^T
// Wt is bf16 [N][K] (pre-transposed). Tile BM x BN, K-step 32, 256 thr = 4 waves,
// wave grid WRM x WRN. mfma_f32_16x16x32_bf16; C/D: col=lane&15,row=(lane>>4)*4+r.
// LDS rows padded to 40 bf16 (80 B) -> 2-way max bank aliasing on ds_read_b128.
// EP=0 plain; EP=1 +e1[n]+e2[act[m]*DM+n]; EP=3 +e1[m*ldc+n] (residual).
// ---------------------------------------------------------------------------
template<int EP, int BM, int BN, int WRM, int WRN>
__global__ __launch_bounds__(256)
void gemm_mfma(const float* __restrict__ A, int lda,
               const short* __restrict__ Wt, int ldw,
               float* __restrict__ C, int ldc, int Kd,
               const float* __restrict__ e1,
               const float* __restrict__ e2,
               const int* __restrict__ act)
{
    constexpr int WM = BM / WRM, WN = BN / WRN;
    constexpr int FM = WM / 16, FN = WN / 16;
    __shared__ short As[BM][40];
    __shared__ short Bs[BN][40];
    const int tid = threadIdx.x;
    const int wave = tid >> 6, lane = tid & 63;
    const int lr = lane & 15, lg = lane >> 4;
    const int wm0 = (wave / WRN) * WM, wn0 = (wave % WRN) * WN;
    const int bm = blockIdx.y * BM, bn = blockIdx.x * BN;

    f32x4 acc[FM][FN];
    #pragma unroll
    for (int fi = 0; fi < FM; fi++)
        #pragma unroll
        for (int fj = 0; fj < FN; fj++)
            acc[fi][fj] = (f32x4){0.f, 0.f, 0.f, 0.f};

    for (int k0 = 0; k0 < Kd; k0 += 32) {
        // stage A tile (BM x 32 fp32 -> bf16), float4 loads, 8B LDS writes
        #pragma unroll
        for (int i = tid; i < BM * 8; i += 256) {
            const int row = i >> 3, seg = i & 7;
            const float4 v = *reinterpret_cast<const float4*>(
                A + (size_t)(bm + row) * lda + k0 + seg * 4);
            uint2 p;
            p.x = (uint)bfbits(v.x) | ((uint)bfbits(v.y) << 16);
            p.y = (uint)bfbits(v.z) | ((uint)bfbits(v.w) << 16);
            *reinterpret_cast<uint2*>(&As[row][seg * 4]) = p;
        }
        // stage B tile (BN x 32 bf16), 16B copies from pre-transposed rows
        #pragma unroll
        for (int i = tid; i < BN * 4; i += 256) {
            const int n = i >> 2, seg = i & 3;
            *reinterpret_cast<uint4*>(&Bs[n][seg * 8]) =
                *reinterpret_cast<const uint4*>(Wt + (size_t)(bn + n) * ldw + k0 + seg * 8);
        }
        __syncthreads();
        bf16x8 af[FM], bfr[FN];
        #pragma unroll
        for (int fi = 0; fi < FM; fi++)
            af[fi] = *reinterpret_cast<const bf16x8*>(&As[wm0 + fi * 16 + lr][lg * 8]);
        #pragma unroll
        for (int fj = 0; fj < FN; fj++)
            bfr[fj] = *reinterpret_cast<const bf16x8*>(&Bs[wn0 + fj * 16 + lr][lg * 8]);
        #pragma unroll
        for (int fi = 0; fi < FM; fi++)
            #pragma unroll
            for (int fj = 0; fj < FN; fj++)
                acc[fi][fj] = __builtin_amdgcn_mfma_f32_16x16x32_bf16(
                    af[fi], bfr[fj], acc[fi][fj], 0, 0, 0);
        __syncthreads();
    }

    #pragma unroll
    for (int fi = 0; fi < FM; fi++) {
        #pragma unroll
        for (int fj = 0; fj < FN; fj++) {
            #pragma unroll
            for (int r = 0; r < 4; r++) {
                const int m = bm + wm0 + fi * 16 + lg * 4 + r;
                const int n = bn + wn0 + fj * 16 + lr;
                float v = acc[fi][fj][r];
                if (EP == 1) v += e1[n] + e2[(size_t)act[m] * DM + n];
                if (EP == 3) v += e1[(size_t)m * ldc + n];
                C[(size_t)m * ldc + n] = v;
            }
        }
    }
}

// ---------------------------------------------------------------------------
// fp32 tiled GEMM (kept for dt: K=32). 64x64 tile, 256 thr, 4x4/thread.
// EP=2: softplus(c + e1[n])
// ---------------------------------------------------------------------------
template<int EP>
__global__ __launch_bounds__(256)
void gemm64(const float* __restrict__ A, int lda,
            const float* __restrict__ Bw, int ldb,
            float* __restrict__ C, int ldc, int Kd,
            const float* __restrict__ e1)
{
    __shared__ float As[16][68];
    __shared__ float Bs[16][68];
    const int tx = threadIdx.x, ty = threadIdx.y;
    const int tid = ty * 16 + tx;
    const int bm = blockIdx.y * 64, bn = blockIdx.x * 64;
    float c[4][4] = {};
    for (int k0 = 0; k0 < Kd; k0 += 16) {
        #pragma unroll
        for (int j = 0; j < 4; j++) {
            int idx = tid + 256 * j;
            int kk = idx & 15, ml = idx >> 4;
            As[kk][ml] = A[(size_t)(bm + ml) * lda + k0 + kk];
        }
        #pragma unroll
        for (int j = 0; j < 4; j++) {
            int idx = tid + 256 * j;
            int nl = idx & 63, kk = idx >> 6;
            Bs[kk][nl] = Bw[(size_t)(k0 + kk) * ldb + bn + nl];
        }
        __syncthreads();
        #pragma unroll
        for (int kk = 0; kk < 16; kk++) {
            float a[4], b[4];
            #pragma unroll
            for (int i = 0; i < 4; i++) a[i] = As[kk][ty * 4 + i];
            #pragma unroll
            for (int i = 0; i < 4; i++) b[i] = Bs[kk][tx * 4 + i];
            #pragma unroll
            for (int i = 0; i < 4; i++)
                #pragma unroll
                for (int j = 0; j < 4; j++)
                    c[i][j] += a[i] * b[j];
        }
        __syncthreads();
    }
    #pragma unroll
    for (int i = 0; i < 4; i++) {
        int m = bm + ty * 4 + i;
        #pragma unroll
        for (int j = 0; j < 4; j++) {
            int n = bn + tx * 4 + j;
            float v = c[i][j];
            if (EP == 2) { v += e1[n]; v = fmaxf(v, 0.f) + log1pf(expf(-fabsf(v))); }
            C[(size_t)m * ldc + n] = v;
        }
    }
}

// ---------------------------------------------------------------------------
// xproj split-K: part[sk][m][64] = xc[m, sk*64:(sk+1)*64] @ W[sk*64:(sk+1)*64, :]
// grid (SK, BT/64), block 16x16, 4x4/thread over a 64x64 tile.
// ---------------------------------------------------------------------------
__global__ __launch_bounds__(256)
void gemm_xproj(const float* __restrict__ A, const float* __restrict__ W,
                float* __restrict__ part)
{
    __shared__ float As[16][68];
    __shared__ float Bs[16][68];
    const int tx = threadIdx.x, ty = threadIdx.y;
    const int tid = ty * 16 + tx;
    const int sk = blockIdx.x;
    const int bm = blockIdx.y * 64;
    float c[4][4] = {};
    for (int k0 = sk * 64; k0 < sk * 64 + 64; k0 += 16) {
        #pragma unroll
        for (int j = 0; j < 4; j++) {
            int idx = tid + 256 * j;
            int kk = idx & 15, ml = idx >> 4;
            As[kk][ml] = A[(size_t)(bm + ml) * DI + k0 + kk];
        }
        #pragma unroll
        for (int j = 0; j < 4; j++) {
            int idx = tid + 256 * j;
            int nl = idx & 63, kk = idx >> 6;
            Bs[kk][nl] = W[(size_t)(k0 + kk) * 64 + nl];
        }
        __syncthreads();
        #pragma unroll
        for (int kk = 0; kk < 16; kk++) {
            float a[4], b[4];
            #pragma unroll
            for (int i = 0; i < 4; i++) a[i] = As[kk][ty * 4 + i];
            #pragma unroll
            for (int i = 0; i < 4; i++) b[i] = Bs[kk][tx * 4 + i];
            #pragma unroll
            for (int i = 0; i < 4; i++)
                #pragma unroll
                for (int j = 0; j < 4; j++)
                    c[i][j] += a[i] * b[j];
        }
        __syncthreads();
    }
    float* Cp = part + ((size_t)sk * BT + bm) * 64;
    #pragma unroll
    for (int i = 0; i < 4; i++)
        #pragma unroll
        for (int j = 0; j < 4; j++)
            Cp[(size_t)(ty * 4 + i) * 64 + tx * 4 + j] = c[i][j];
}

__global__ __launch_bounds__(256)
void xproj_reduce(const float* __restrict__ part, float* __restrict__ dbc)
{
    const int idx = blockIdx.x * 256 + threadIdx.x;   // BT*64
    float s = 0.f;
    #pragma unroll
    for (int sk = 0; sk < SK; sk++) s += part[(size_t)sk * BT * 64 + idx];
    dbc[idx] = s;
}

// ---------------------------------------------------------------------------
// LayerNorm over rows of length DM. grid = rows, block = 256.
// ---------------------------------------------------------------------------
__global__ __launch_bounds__(256)
void ln_kernel(const float* __restrict__ x, const float* __restrict__ w,
               const float* __restrict__ bb, float* __restrict__ o)
{
    const int row = blockIdx.x;
    const int tid = threadIdx.x;
    const float* xr = x + (size_t)row * DM;
    float s = 0.f, ss = 0.f;
    for (int i = tid; i < DM; i += 256) { float v = xr[i]; s += v; ss += v * v; }
    #pragma unroll
    for (int m = 32; m >= 1; m >>= 1) { s += __shfl_xor(s, m, 64); ss += __shfl_xor(ss, m, 64); }
    __shared__ float sm[4], sm2[4];
    const int wv = tid >> 6;
    if ((tid & 63) == 0) { sm[wv] = s; sm2[wv] = ss; }
    __syncthreads();
    s  = sm[0] + sm[1] + sm[2] + sm[3];
    ss = sm2[0] + sm2[1] + sm2[2] + sm2[3];
    const float mean = s * (1.f / DM);
    float var = ss * (1.f / DM) - mean * mean;
    var = fmaxf(var, 0.f);
    const float rstd = rsqrtf(var + EPSV);
    for (int i = tid; i < DM; i += 256) {
        float v = (xr[i] - mean) * rstd;
        o[(size_t)row * DM + i] = v * w[i] + bb[i];
    }
}

// ---------------------------------------------------------------------------
// Causal depthwise conv (K=4) + SiLU.  xin = xz[:, :DI] (row stride 2048).
// ---------------------------------------------------------------------------
__global__ __launch_bounds__(256)
void conv_silu(const float* __restrict__ xz, const float* __restrict__ cw,
               const float* __restrict__ cb, float* __restrict__ xc)
{
    const int idx = blockIdx.x * 256 + threadIdx.x;   // over BT*DI
    const int d = idx & (DI - 1);
    const int bt = idx >> 10;
    const int t = bt & (T_ - 1);
    float acc = cb[d];
    #pragma unroll
    for (int k = 0; k < KC; k++) {
        int sh = 3 - k;
        if (t >= sh) acc += cw[d * KC + k] * xz[(size_t)(bt - sh) * 2048 + d];
    }
    const float sg = 1.f / (1.f + expf(-acc));
    xc[idx] = acc * sg;
}

// ---------------------------------------------------------------------------
// Chunked selective scan, pass A: per-chunk local scan (h0 = 0).
// ---------------------------------------------------------------------------
__global__ __launch_bounds__(256)
void scan_passA(const float* __restrict__ dt, const float* __restrict__ xc,
                const float* __restrict__ dbc, const float* __restrict__ A_log,
                float* __restrict__ Aprod, float* __restrict__ hloc)
{
    const int blk = blockIdx.x;
    const int c  = blk & (CH - 1);
    const int dg = (blk >> 4) & 63;
    const int b  = blk >> 10;
    const int tid = threadIdx.x;
    const int s = tid & 15;
    const int dl = tid >> 4;
    const int d = dg * 16 + dl;

    const float Aval = -expf(A_log[(size_t)d * DS + s]);
    float h = 0.f, ap = 1.f;
    const size_t base = (size_t)b * T_ + c * TC;

    #pragma unroll 4
    for (int t = 0; t < TC; t++) {
        const size_t r = base + t;
        const float dtv = dt[r * DI + d];
        const float xv  = xc[r * DI + d];
        const float Bv  = dbc[r * 64 + 32 + s];
        const float a = expf(dtv * Aval);
        h = a * h + (dtv * xv) * Bv;
        ap *= a;
    }
    const size_t o = ((size_t)(b * CH + c) * DI) * DS + dg * 256 + tid;
    Aprod[o] = ap;
    hloc[o]  = h;
}

// ---------------------------------------------------------------------------
// Chunked selective scan, pass C: fold upstream summaries, recompute, emit y.
// ---------------------------------------------------------------------------
__global__ __launch_bounds__(256)
void scan_passC(const float* __restrict__ dt, const float* __restrict__ xc,
                const float* __restrict__ dbc, const float* __restrict__ xz,
                const float* __restrict__ A_log, const float* __restrict__ Dskip,
                const float* __restrict__ Aprod, const float* __restrict__ hloc,
                float* __restrict__ y)
{
    const int blk = blockIdx.x;
    const int c  = blk & (CH - 1);
    const int dg = (blk >> 4) & 63;
    const int b  = blk >> 10;
    const int tid = threadIdx.x;
    const int s = tid & 15;
    const int dl = tid >> 4;
    const int d = dg * 16 + dl;

    float h = 0.f;
    const size_t obase = (size_t)b * CH * DI * DS + dg * 256 + tid;
    for (int cc = 0; cc < c; cc++) {
        const size_t o = obase + (size_t)cc * DI * DS;
        h = Aprod[o] * h + hloc[o];
    }

    const float Aval = -expf(A_log[(size_t)d * DS + s]);
    const float Dv = Dskip[d];
    const size_t base = (size_t)b * T_ + c * TC;

    #pragma unroll 2
    for (int t = 0; t < TC; t++) {
        const size_t r = base + t;
        const float dtv = dt[r * DI + d];
        const float xv  = xc[r * DI + d];
        const float Bv  = dbc[r * 64 + 32 + s];
        const float Cv  = dbc[r * 64 + 48 + s];
        const float a = expf(dtv * Aval);
        h = a * h + (dtv * xv) * Bv;
        float p = h * Cv;
        p += __shfl_xor(p, 1, 16);
        p += __shfl_xor(p, 2, 16);
        p += __shfl_xor(p, 4, 16);
        p += __shfl_xor(p, 8, 16);
        if (s == 0) {
            const float zv = xz[r * 2048 + 1024 + d];
            const float sg = 1.f / (1.f + expf(-zv));
            y[r * DI + d] = (p + Dv * xv) * (zv * sg);
        }
    }
}

// ---------------------------------------------------------------------------
__global__ __launch_bounds__(256)
void mean_kernel(const float* __restrict__ x, float* __restrict__ out)
{
    const int idx = blockIdx.x * 256 + threadIdx.x;   // B*DM
    const int b = idx / DM;
    const int dcol = idx % DM;
    float ssum = 0.f;
    for (int t = 0; t < T_; t++) ssum += x[((size_t)b * T_ + t) * DM + dcol];
    out[idx] = ssum * (1.f / T_);
}

// ---------------------------------------------------------------------------
extern "C" void kernel_launch(void* const* d_in, const int* in_sizes, int n_in,
                              void* d_out, int out_size, void* d_ws, size_t ws_size,
                              hipStream_t stream)
{
    const float* samples  = (const float*)d_in[0];
    const int*   actions  = (const int*)  d_in[1];
    const float* W_embed  = (const float*)d_in[2];
    const float* b_embed  = (const float*)d_in[3];
    const float* act_emb  = (const float*)d_in[4];
    const float* ln_w     = (const float*)d_in[5];
    const float* ln_b     = (const float*)d_in[6];
    const float* W_in     = (const float*)d_in[7];
    const float* conv_w   = (const float*)d_in[8];
    const float* conv_b   = (const float*)d_in[9];
    const float* W_xproj  = (const float*)d_in[10];
    const float* W_dt     = (const float*)d_in[11];
    const float* b_dt     = (const float*)d_in[12];
    const float* A_log    = (const float*)d_in[13];
    const float* D_skip   = (const float*)d_in[14];
    const float* W_out    = (const float*)d_in[15];
    const float* normf_w  = (const float*)d_in[16];
    const float* normf_b  = (const float*)d_in[17];
    const float* out_ln_w = (const float*)d_in[18];
    const float* out_ln_b = (const float*)d_in[19];

    float* ws  = (float*)d_ws;
    float* x    = ws;                          // BT*DM
    float* h    = x    + (size_t)BT * DM;      // BT*DM
    float* xz   = h    + (size_t)BT * DM;      // BT*2048
    float* xc   = xz   + (size_t)BT * 2048;    // BT*DI
    float* dbc  = xc   + (size_t)BT * DI;      // BT*64
    float* dtb  = dbc  + (size_t)BT * 64;      // BT*DI
    float* yg   = dtb  + (size_t)BT * DI;      // BT*DI
    float* Apr  = yg   + (size_t)BT * DI;      // B*CH*DI*DS
    float* hlo  = Apr  + (size_t)B_ * CH * DI * DS;  // B*CH*DI*DS
    float* part = Apr;                         // alias: SK*BT*64 == 2*B*CH*DI*DS
    float* wb   = hlo  + (size_t)B_ * CH * DI * DS;
    short* WtE  = (short*)wb;                        // [DM][STOCH]
    short* WtI  = WtE + (size_t)DM * STOCH;          // 4 x [2048][DM]
    short* WtO  = WtI + (size_t)4 * 2048 * DM;       // 4 x [DM][DI]

    dim3 blk2(16, 16);

    // one-time per call: weights -> bf16, transposed [N][K]
    wconvT<<<dim3(DM / 32, STOCH / 32, 1), dim3(32, 8), 0, stream>>>(W_embed, WtE, STOCH, DM);
    wconvT<<<dim3(2048 / 32, DM / 32, 4), dim3(32, 8), 0, stream>>>(W_in, WtI, DM, 2048);
    wconvT<<<dim3(DM / 32, DI / 32, 4), dim3(32, 8), 0, stream>>>(W_out, WtO, DI, DM);

    // x = samples @ W_embed + b_embed + act_embed[actions]
    gemm_mfma<1, 64, 64, 2, 2><<<dim3(DM / 64, BT / 64), 256, 0, stream>>>(
        samples, STOCH, WtE, STOCH, x, DM, STOCH, b_embed, act_emb, actions);

    for (int l = 0; l < NL; l++) {
        ln_kernel<<<BT, 256, 0, stream>>>(x, ln_w + l * DM, ln_b + l * DM, h);
        // xz = h @ W_in[l]
        gemm_mfma<0, 128, 64, 4, 1><<<dim3(2048 / 64, BT / 128), 256, 0, stream>>>(
            h, DM, WtI + (size_t)l * 2048 * DM, DM, xz, 2048, DM,
            nullptr, nullptr, nullptr);
        conv_silu<<<(BT * DI) / 256, 256, 0, stream>>>(
            xz, conv_w + (size_t)l * DI * KC, conv_b + (size_t)l * DI, xc);
        // dbc = xc @ W_xproj[l]  (split-K + reduce)
        gemm_xproj<<<dim3(SK, BT / 64), blk2, 0, stream>>>(
            xc, W_xproj + (size_t)l * DI * 64, part);
        xproj_reduce<<<(BT * 64) / 256, 256, 0, stream>>>(part, dbc);
        // dt = softplus(dbc[:, :32] @ W_dt[l] + b_dt[l])
        gemm64<2><<<dim3(DI / 64, BT / 64), blk2, 0, stream>>>(
            dbc, 64, W_dt + (size_t)l * DTR * DI, DI, dtb, DI, DTR,
            b_dt + (size_t)l * DI);
        scan_passA<<<B_ * (DI / 16) * CH, 256, 0, stream>>>(
            dtb, xc, dbc, A_log + (size_t)l * DI * DS, Apr, hlo);
        scan_passC<<<B_ * (DI / 16) * CH, 256, 0, stream>>>(
            dtb, xc, dbc, xz, A_log + (size_t)l * DI * DS, D_skip + (size_t)l * DI,
            Apr, hlo, yg);
        // x = x + yg @ W_out[l]
        gemm_mfma<3, 64, 64, 2, 2><<<dim3(DM / 64, BT / 64), 256, 0, stream>>>(
            yg, DI, WtO + (size_t)l * DM * DI, DI, x, DM, DI,
            x, nullptr, nullptr);
    }

    ln_kernel<<<BT, 256, 0, stream>>>(x, normf_w, normf_b, h);
    ln_kernel<<<BT, 256, 0, stream>>>(h, out_ln_w, out_ln_b, yg);
    mean_kernel<<<(B_ * DM) / 256, 256, 0, stream>>>(yg, (float*)d_out);
}

// Round 4
// 648.052 us; speedup vs baseline: 3.8511x; 1.3139x over previous
//
#include <hip/hip_runtime.h>
#include <hip/hip_bf16.h>
#include <math.h>

// Problem constants (from reference)
#define B_    4
#define T_    512
#define BT    2048      // B*T rows
#define STOCH 1024
#define DM    512       // d_model
#define DI    1024      // d_inner
#define DS    16        // d_state
#define DTR   32        // dt_rank
#define KC    4         // conv kernel
#define NL    4         // layers
#define EPSV  1e-5f
#define CH    32        // scan chunks
#define TC    16        // T_/CH steps per chunk
#define SK    16        // xproj split-K slices

typedef short bf16x8 __attribute__((ext_vector_type(8)));
typedef float f32x4  __attribute__((ext_vector_type(4)));

__device__ __forceinline__ ushort bfbits(float f) {
    uint u = __float_as_uint(f);
    u += 0x7FFFu + ((u >> 16) & 1u);       // RTNE
    return (ushort)(u >> 16);
}

// ---------------------------------------------------------------------------
// Batched weight convert+transpose: W[K][N] fp32 -> Wt[N][K] bf16.
// ---------------------------------------------------------------------------
__global__ __launch_bounds__(256)
void wconvT(const float* __restrict__ W, short* __restrict__ Wt, int K, int N)
{
    const float* Wb = W + (size_t)blockIdx.z * K * N;
    short* Wtb = Wt + (size_t)blockIdx.z * K * N;
    __shared__ float tile[32][33];
    const int tx = threadIdx.x, ty = threadIdx.y;
    const int n0 = blockIdx.x * 32, k0 = blockIdx.y * 32;
    #pragma unroll
    for (int j = 0; j < 4; j++)
        tile[ty + j * 8][tx] = Wb[(size_t)(k0 + ty + j * 8) * N + n0 + tx];
    __syncthreads();
    #pragma unroll
    for (int j = 0; j < 4; j++) {
        const int n = ty + j * 8;
        Wtb[(size_t)(n0 + n) * K + k0 + tx] = (short)bfbits(tile[tx][n]);
    }
}

// ---------------------------------------------------------------------------
// bf16 MFMA GEMM (unchanged from R3). C/D: col=lane&15,row=(lane>>4)*4+r.
// ---------------------------------------------------------------------------
template<int EP, int BM, int BN, int WRM, int WRN>
__global__ __launch_bounds__(256)
void gemm_mfma(const float* __restrict__ A, int lda,
               const short* __restrict__ Wt, int ldw,
               float* __restrict__ C, int ldc, int Kd,
               const float* __restrict__ e1,
               const float* __restrict__ e2,
               const int* __restrict__ act)
{
    constexpr int WM = BM / WRM, WN = BN / WRN;
    constexpr int FM = WM / 16, FN = WN / 16;
    __shared__ short As[BM][40];
    __shared__ short Bs[BN][40];
    const int tid = threadIdx.x;
    const int wave = tid >> 6, lane = tid & 63;
    const int lr = lane & 15, lg = lane >> 4;
    const int wm0 = (wave / WRN) * WM, wn0 = (wave % WRN) * WN;
    const int bm = blockIdx.y * BM, bn = blockIdx.x * BN;

    f32x4 acc[FM][FN];
    #pragma unroll
    for (int fi = 0; fi < FM; fi++)
        #pragma unroll
        for (int fj = 0; fj < FN; fj++)
            acc[fi][fj] = (f32x4){0.f, 0.f, 0.f, 0.f};

    for (int k0 = 0; k0 < Kd; k0 += 32) {
        #pragma unroll
        for (int i = tid; i < BM * 8; i += 256) {
            const int row = i >> 3, seg = i & 7;
            const float4 v = *reinterpret_cast<const float4*>(
                A + (size_t)(bm + row) * lda + k0 + seg * 4);
            uint2 p;
            p.x = (uint)bfbits(v.x) | ((uint)bfbits(v.y) << 16);
            p.y = (uint)bfbits(v.z) | ((uint)bfbits(v.w) << 16);
            *reinterpret_cast<uint2*>(&As[row][seg * 4]) = p;
        }
        #pragma unroll
        for (int i = tid; i < BN * 4; i += 256) {
            const int n = i >> 2, seg = i & 3;
            *reinterpret_cast<uint4*>(&Bs[n][seg * 8]) =
                *reinterpret_cast<const uint4*>(Wt + (size_t)(bn + n) * ldw + k0 + seg * 8);
        }
        __syncthreads();
        bf16x8 af[FM], bfr[FN];
        #pragma unroll
        for (int fi = 0; fi < FM; fi++)
            af[fi] = *reinterpret_cast<const bf16x8*>(&As[wm0 + fi * 16 + lr][lg * 8]);
        #pragma unroll
        for (int fj = 0; fj < FN; fj++)
            bfr[fj] = *reinterpret_cast<const bf16x8*>(&Bs[wn0 + fj * 16 + lr][lg * 8]);
        #pragma unroll
        for (int fi = 0; fi < FM; fi++)
            #pragma unroll
            for (int fj = 0; fj < FN; fj++)
                acc[fi][fj] = __builtin_amdgcn_mfma_f32_16x16x32_bf16(
                    af[fi], bfr[fj], acc[fi][fj], 0, 0, 0);
        __syncthreads();
    }

    #pragma unroll
    for (int fi = 0; fi < FM; fi++) {
        #pragma unroll
        for (int fj = 0; fj < FN; fj++) {
            #pragma unroll
            for (int r = 0; r < 4; r++) {
                const int m = bm + wm0 + fi * 16 + lg * 4 + r;
                const int n = bn + wn0 + fj * 16 + lr;
                float v = acc[fi][fj][r];
                if (EP == 1) v += e1[n] + e2[(size_t)act[m] * DM + n];
                if (EP == 3) v += e1[(size_t)m * ldc + n];
                C[(size_t)m * ldc + n] = v;
            }
        }
    }
}

// ---------------------------------------------------------------------------
// fp32 tiled GEMM (dt: K=32). EP=2: softplus(c + e1[n])
// ---------------------------------------------------------------------------
template<int EP>
__global__ __launch_bounds__(256)
void gemm64(const float* __restrict__ A, int lda,
            const float* __restrict__ Bw, int ldb,
            float* __restrict__ C, int ldc, int Kd,
            const float* __restrict__ e1)
{
    __shared__ float As[16][68];
    __shared__ float Bs[16][68];
    const int tx = threadIdx.x, ty = threadIdx.y;
    const int tid = ty * 16 + tx;
    const int bm = blockIdx.y * 64, bn = blockIdx.x * 64;
    float c[4][4] = {};
    for (int k0 = 0; k0 < Kd; k0 += 16) {
        #pragma unroll
        for (int j = 0; j < 4; j++) {
            int idx = tid + 256 * j;
            int kk = idx & 15, ml = idx >> 4;
            As[kk][ml] = A[(size_t)(bm + ml) * lda + k0 + kk];
        }
        #pragma unroll
        for (int j = 0; j < 4; j++) {
            int idx = tid + 256 * j;
            int nl = idx & 63, kk = idx >> 6;
            Bs[kk][nl] = Bw[(size_t)(k0 + kk) * ldb + bn + nl];
        }
        __syncthreads();
        #pragma unroll
        for (int kk = 0; kk < 16; kk++) {
            float a[4], b[4];
            #pragma unroll
            for (int i = 0; i < 4; i++) a[i] = As[kk][ty * 4 + i];
            #pragma unroll
            for (int i = 0; i < 4; i++) b[i] = Bs[kk][tx * 4 + i];
            #pragma unroll
            for (int i = 0; i < 4; i++)
                #pragma unroll
                for (int j = 0; j < 4; j++)
                    c[i][j] += a[i] * b[j];
        }
        __syncthreads();
    }
    #pragma unroll
    for (int i = 0; i < 4; i++) {
        int m = bm + ty * 4 + i;
        #pragma unroll
        for (int j = 0; j < 4; j++) {
            int n = bn + tx * 4 + j;
            float v = c[i][j];
            if (EP == 2) { v += e1[n]; v = fmaxf(v, 0.f) + log1pf(expf(-fabsf(v))); }
            C[(size_t)m * ldc + n] = v;
        }
    }
}

// ---------------------------------------------------------------------------
// xproj split-K + reduce (unchanged)
// ---------------------------------------------------------------------------
__global__ __launch_bounds__(256)
void gemm_xproj(const float* __restrict__ A, const float* __restrict__ W,
                float* __restrict__ part)
{
    __shared__ float As[16][68];
    __shared__ float Bs[16][68];
    const int tx = threadIdx.x, ty = threadIdx.y;
    const int tid = ty * 16 + tx;
    const int sk = blockIdx.x;
    const int bm = blockIdx.y * 64;
    float c[4][4] = {};
    for (int k0 = sk * 64; k0 < sk * 64 + 64; k0 += 16) {
        #pragma unroll
        for (int j = 0; j < 4; j++) {
            int idx = tid + 256 * j;
            int kk = idx & 15, ml = idx >> 4;
            As[kk][ml] = A[(size_t)(bm + ml) * DI + k0 + kk];
        }
        #pragma unroll
        for (int j = 0; j < 4; j++) {
            int idx = tid + 256 * j;
            int nl = idx & 63, kk = idx >> 6;
            Bs[kk][nl] = W[(size_t)(k0 + kk) * 64 + nl];
        }
        __syncthreads();
        #pragma unroll
        for (int kk = 0; kk < 16; kk++) {
            float a[4], b[4];
            #pragma unroll
            for (int i = 0; i < 4; i++) a[i] = As[kk][ty * 4 + i];
            #pragma unroll
            for (int i = 0; i < 4; i++) b[i] = Bs[kk][tx * 4 + i];
            #pragma unroll
            for (int i = 0; i < 4; i++)
                #pragma unroll
                for (int j = 0; j < 4; j++)
                    c[i][j] += a[i] * b[j];
        }
        __syncthreads();
    }
    float* Cp = part + ((size_t)sk * BT + bm) * 64;
    #pragma unroll
    for (int i = 0; i < 4; i++)
        #pragma unroll
        for (int j = 0; j < 4; j++)
            Cp[(size_t)(ty * 4 + i) * 64 + tx * 4 + j] = c[i][j];
}

__global__ __launch_bounds__(256)
void xproj_reduce(const float* __restrict__ part, float* __restrict__ dbc)
{
    const int idx = blockIdx.x * 256 + threadIdx.x;   // BT*64
    float s = 0.f;
    #pragma unroll
    for (int sk = 0; sk < SK; sk++) s += part[(size_t)sk * BT * 64 + idx];
    dbc[idx] = s;
}

// ---------------------------------------------------------------------------
// LayerNorm over rows of length DM.
// ---------------------------------------------------------------------------
__global__ __launch_bounds__(256)
void ln_kernel(const float* __restrict__ x, const float* __restrict__ w,
               const float* __restrict__ bb, float* __restrict__ o)
{
    const int row = blockIdx.x;
    const int tid = threadIdx.x;
    const float* xr = x + (size_t)row * DM;
    float s = 0.f, ss = 0.f;
    for (int i = tid; i < DM; i += 256) { float v = xr[i]; s += v; ss += v * v; }
    #pragma unroll
    for (int m = 32; m >= 1; m >>= 1) { s += __shfl_xor(s, m, 64); ss += __shfl_xor(ss, m, 64); }
    __shared__ float sm[4], sm2[4];
    const int wv = tid >> 6;
    if ((tid & 63) == 0) { sm[wv] = s; sm2[wv] = ss; }
    __syncthreads();
    s  = sm[0] + sm[1] + sm[2] + sm[3];
    ss = sm2[0] + sm2[1] + sm2[2] + sm2[3];
    const float mean = s * (1.f / DM);
    float var = ss * (1.f / DM) - mean * mean;
    var = fmaxf(var, 0.f);
    const float rstd = rsqrtf(var + EPSV);
    for (int i = tid; i < DM; i += 256) {
        float v = (xr[i] - mean) * rstd;
        o[(size_t)row * DM + i] = v * w[i] + bb[i];
    }
}

// ---------------------------------------------------------------------------
// Causal depthwise conv (K=4) + SiLU.
// ---------------------------------------------------------------------------
__global__ __launch_bounds__(256)
void conv_silu(const float* __restrict__ xz, const float* __restrict__ cw,
               const float* __restrict__ cb, float* __restrict__ xc)
{
    const int idx = blockIdx.x * 256 + threadIdx.x;   // over BT*DI
    const int d = idx & (DI - 1);
    const int bt = idx >> 10;
    const int t = bt & (T_ - 1);
    float acc = cb[d];
    #pragma unroll
    for (int k = 0; k < KC; k++) {
        int sh = 3 - k;
        if (t >= sh) acc += cw[d * KC + k] * xz[(size_t)(bt - sh) * 2048 + d];
    }
    const float sg = 1.f / (1.f + __expf(-acc));
    xc[idx] = acc * sg;
}

// ---------------------------------------------------------------------------
// Scan pass A: one thread per (b,chunk,d); all 16 states in registers.
// Writes chunk summaries Aprod/hloc, layout [b][c][s][d] (d fastest, coalesced).
// ---------------------------------------------------------------------------
__global__ __launch_bounds__(256)
void scan_passA(const float* __restrict__ dt, const float* __restrict__ xc,
                const float* __restrict__ dbc, const float* __restrict__ A_log,
                float* __restrict__ Aprod, float* __restrict__ hloc)
{
    const int blk = blockIdx.x;
    const int dg = blk & 3;
    const int c  = (blk >> 2) & (CH - 1);
    const int b  = blk >> 7;
    const int d  = dg * 256 + threadIdx.x;
    const size_t base = (size_t)b * T_ + c * TC;

    __shared__ float Bsh[TC][DS];
    {
        const int i = threadIdx.x;   // TC*DS = 256
        const int t = i >> 4, s = i & 15;
        Bsh[t][s] = dbc[(base + t) * 64 + 32 + s];
    }
    __syncthreads();

    float Aval[DS], h[DS], ap[DS];
    #pragma unroll
    for (int s = 0; s < DS; s++) {
        Aval[s] = -__expf(A_log[(size_t)d * DS + s]);
        h[s] = 0.f; ap[s] = 1.f;
    }

    #pragma unroll 4
    for (int t = 0; t < TC; t++) {
        const size_t r = base + t;
        const float dtv = dt[r * DI + d];
        const float xv  = xc[r * DI + d];
        const float u = dtv * xv;
        #pragma unroll
        for (int s = 0; s < DS; s++) {
            const float a = __expf(dtv * Aval[s]);
            h[s] = a * h[s] + u * Bsh[t][s];
            ap[s] *= a;
        }
    }
    const size_t o0 = ((size_t)(b * CH + c) * DS) * DI + d;
    #pragma unroll
    for (int s = 0; s < DS; s++) {
        Aprod[o0 + (size_t)s * DI] = ap[s];
        hloc[o0 + (size_t)s * DI]  = h[s];
    }
}

// ---------------------------------------------------------------------------
// Scan pass B: per (b,s,d) thread folds chunk summaries sequentially,
// overwriting hloc[c] with the chunk's STARTING state h0 (in-place).
// ---------------------------------------------------------------------------
__global__ __launch_bounds__(256)
void scan_passB(const float* __restrict__ Aprod, float* __restrict__ hloc)
{
    const int idx = blockIdx.x * 256 + threadIdx.x;   // B*DS*DI = 65536
    const int d = idx & (DI - 1);
    const int s = (idx >> 10) & (DS - 1);
    const int b = idx >> 14;
    float h = 0.f;
    for (int c = 0; c < CH; c++) {
        const size_t o = ((size_t)(b * CH + c) * DS + s) * DI + d;
        const float a  = Aprod[o];
        const float hl = hloc[o];
        hloc[o] = h;                 // h0 for chunk c
        h = a * h + hl;
    }
}

// ---------------------------------------------------------------------------
// Scan pass C: one thread per (b,chunk,d); loads h0, recomputes chunk,
// emits y = (sum_s h*C + D*x) * silu(z). No cross-lane ops.
// ---------------------------------------------------------------------------
__global__ __launch_bounds__(256)
void scan_passC(const float* __restrict__ dt, const float* __restrict__ xc,
                const float* __restrict__ dbc, const float* __restrict__ xz,
                const float* __restrict__ A_log, const float* __restrict__ Dskip,
                const float* __restrict__ h0buf, float* __restrict__ y)
{
    const int blk = blockIdx.x;
    const int dg = blk & 3;
    const int c  = (blk >> 2) & (CH - 1);
    const int b  = blk >> 7;
    const int d  = dg * 256 + threadIdx.x;
    const size_t base = (size_t)b * T_ + c * TC;

    __shared__ float Bsh[TC][DS];
    __shared__ float Csh[TC][DS];
    for (int i = threadIdx.x; i < TC * 32; i += 256) {
        const int t = i >> 5, sc = i & 31;
        const float v = dbc[(base + t) * 64 + 32 + sc];
        if (sc < 16) Bsh[t][sc] = v; else Csh[t][sc - 16] = v;
    }
    __syncthreads();

    float Aval[DS], h[DS];
    const size_t o0 = ((size_t)(b * CH + c) * DS) * DI + d;
    #pragma unroll
    for (int s = 0; s < DS; s++) {
        Aval[s] = -__expf(A_log[(size_t)d * DS + s]);
        h[s] = h0buf[o0 + (size_t)s * DI];
    }
    const float Dv = Dskip[d];

    #pragma unroll 2
    for (int t = 0; t < TC; t++) {
        const size_t r = base + t;
        const float dtv = dt[r * DI + d];
        const float xv  = xc[r * DI + d];
        const float u = dtv * xv;
        float yacc = 0.f;
        #pragma unroll
        for (int s = 0; s < DS; s++) {
            const float a = __expf(dtv * Aval[s]);
            h[s] = a * h[s] + u * Bsh[t][s];
            yacc += h[s] * Csh[t][s];
        }
        const float zv = xz[r * 2048 + 1024 + d];
        const float sg = 1.f / (1.f + __expf(-zv));
        y[r * DI + d] = (yacc + Dv * xv) * (zv * sg);
    }
}

// ---------------------------------------------------------------------------
__global__ __launch_bounds__(256)
void mean_kernel(const float* __restrict__ x, float* __restrict__ out)
{
    const int idx = blockIdx.x * 256 + threadIdx.x;   // B*DM
    const int b = idx / DM;
    const int dcol = idx % DM;
    float ssum = 0.f;
    for (int t = 0; t < T_; t++) ssum += x[((size_t)b * T_ + t) * DM + dcol];
    out[idx] = ssum * (1.f / T_);
}

// ---------------------------------------------------------------------------
extern "C" void kernel_launch(void* const* d_in, const int* in_sizes, int n_in,
                              void* d_out, int out_size, void* d_ws, size_t ws_size,
                              hipStream_t stream)
{
    const float* samples  = (const float*)d_in[0];
    const int*   actions  = (const int*)  d_in[1];
    const float* W_embed  = (const float*)d_in[2];
    const float* b_embed  = (const float*)d_in[3];
    const float* act_emb  = (const float*)d_in[4];
    const float* ln_w     = (const float*)d_in[5];
    const float* ln_b     = (const float*)d_in[6];
    const float* W_in     = (const float*)d_in[7];
    const float* conv_w   = (const float*)d_in[8];
    const float* conv_b   = (const float*)d_in[9];
    const float* W_xproj  = (const float*)d_in[10];
    const float* W_dt     = (const float*)d_in[11];
    const float* b_dt     = (const float*)d_in[12];
    const float* A_log    = (const float*)d_in[13];
    const float* D_skip   = (const float*)d_in[14];
    const float* W_out    = (const float*)d_in[15];
    const float* normf_w  = (const float*)d_in[16];
    const float* normf_b  = (const float*)d_in[17];
    const float* out_ln_w = (const float*)d_in[18];
    const float* out_ln_b = (const float*)d_in[19];

    float* ws  = (float*)d_ws;
    float* x    = ws;                          // BT*DM          (1M)
    float* h    = x    + (size_t)BT * DM;      // BT*DM          (1M)
    float* xz   = h    + (size_t)BT * DM;      // BT*2048        (4M)
    float* xc   = xz   + (size_t)BT * 2048;    // BT*DI          (2M)
    float* dbc  = xc   + (size_t)BT * DI;      // BT*64          (128K)
    float* dtb  = dbc  + (size_t)BT * 64;      // BT*DI          (2M)
    float* yg   = dtb  + (size_t)BT * DI;      // BT*DI          (2M)
    float* Apr  = yg   + (size_t)BT * DI;      // B*CH*DS*DI     (2M)
    float* hlo  = Apr  + (size_t)B_ * CH * DI * DS;  // same     (2M)
    float* part = Apr;                         // alias: SK*BT*64 == B*CH*DS*DI
    float* wb   = hlo  + (size_t)B_ * CH * DI * DS;
    short* WtE  = (short*)wb;                        // [DM][STOCH]
    short* WtI  = WtE + (size_t)DM * STOCH;          // 4 x [2048][DM]
    short* WtO  = WtI + (size_t)4 * 2048 * DM;       // 4 x [DM][DI]

    dim3 blk2(16, 16);

    // one-time per call: weights -> bf16, transposed [N][K]
    wconvT<<<dim3(DM / 32, STOCH / 32, 1), dim3(32, 8), 0, stream>>>(W_embed, WtE, STOCH, DM);
    wconvT<<<dim3(2048 / 32, DM / 32, 4), dim3(32, 8), 0, stream>>>(W_in, WtI, DM, 2048);
    wconvT<<<dim3(DM / 32, DI / 32, 4), dim3(32, 8), 0, stream>>>(W_out, WtO, DI, DM);

    // x = samples @ W_embed + b_embed + act_embed[actions]
    gemm_mfma<1, 64, 64, 2, 2><<<dim3(DM / 64, BT / 64), 256, 0, stream>>>(
        samples, STOCH, WtE, STOCH, x, DM, STOCH, b_embed, act_emb, actions);

    for (int l = 0; l < NL; l++) {
        ln_kernel<<<BT, 256, 0, stream>>>(x, ln_w + l * DM, ln_b + l * DM, h);
        gemm_mfma<0, 128, 64, 4, 1><<<dim3(2048 / 64, BT / 128), 256, 0, stream>>>(
            h, DM, WtI + (size_t)l * 2048 * DM, DM, xz, 2048, DM,
            nullptr, nullptr, nullptr);
        conv_silu<<<(BT * DI) / 256, 256, 0, stream>>>(
            xz, conv_w + (size_t)l * DI * KC, conv_b + (size_t)l * DI, xc);
        gemm_xproj<<<dim3(SK, BT / 64), blk2, 0, stream>>>(
            xc, W_xproj + (size_t)l * DI * 64, part);
        xproj_reduce<<<(BT * 64) / 256, 256, 0, stream>>>(part, dbc);
        gemm64<2><<<dim3(DI / 64, BT / 64), blk2, 0, stream>>>(
            dbc, 64, W_dt + (size_t)l * DTR * DI, DI, dtb, DI, DTR,
            b_dt + (size_t)l * DI);
        scan_passA<<<B_ * CH * (DI / 256), 256, 0, stream>>>(
            dtb, xc, dbc, A_log + (size_t)l * DI * DS, Apr, hlo);
        scan_passB<<<(B_ * DS * DI) / 256, 256, 0, stream>>>(Apr, hlo);
        scan_passC<<<B_ * CH * (DI / 256), 256, 0, stream>>>(
            dtb, xc, dbc, xz, A_log + (size_t)l * DI * DS, D_skip + (size_t)l * DI,
            hlo, yg);
        gemm_mfma<3, 64, 64, 2, 2><<<dim3(DM / 64, BT / 64), 256, 0, stream>>>(
            yg, DI, WtO + (size_t)l * DM * DI, DI, x, DM, DI,
            x, nullptr, nullptr);
    }

    ln_kernel<<<BT, 256, 0, stream>>>(x, normf_w, normf_b, h);
    ln_kernel<<<BT, 256, 0, stream>>>(h, out_ln_w, out_ln_b, yg);
    mean_kernel<<<(B_ * DM) / 256, 256, 0, stream>>>(yg, (float*)d_out);
}

// Round 5
// 491.815 us; speedup vs baseline: 5.0745x; 1.3177x over previous
//
#include <hip/hip_runtime.h>
#include <hip/hip_bf16.h>
#include <math.h>

// Problem constants (from reference)
#define B_    4
#define T_    512
#define BT    2048      // B*T rows
#define STOCH 1024
#define DM    512       // d_model
#define DI    1024      // d_inner
#define DS    16        // d_state
#define DTR   32        // dt_rank
#define KC    4         // conv kernel
#define NL    4         // layers
#define EPSV  1e-5f
#define CH    32        // scan chunks
#define TC    16        // T_/CH steps per chunk
#define SK    16        // xproj split-K slices
#define GKS   4         // gemm split-K slices (embed / W_out)

typedef short bf16x8 __attribute__((ext_vector_type(8)));
typedef float f32x4  __attribute__((ext_vector_type(4)));

__device__ __forceinline__ ushort bfbits(float f) {
    uint u = __float_as_uint(f);
    u += 0x7FFFu + ((u >> 16) & 1u);       // RTNE
    return (ushort)(u >> 16);
}

// ---------------------------------------------------------------------------
// Batched weight convert+transpose: W[K][N] fp32 -> Wt[N][K] bf16.
// ---------------------------------------------------------------------------
__global__ __launch_bounds__(256)
void wconvT(const float* __restrict__ W, short* __restrict__ Wt, int K, int N)
{
    const float* Wb = W + (size_t)blockIdx.z * K * N;
    short* Wtb = Wt + (size_t)blockIdx.z * K * N;
    __shared__ float tile[32][33];
    const int tx = threadIdx.x, ty = threadIdx.y;
    const int n0 = blockIdx.x * 32, k0 = blockIdx.y * 32;
    #pragma unroll
    for (int j = 0; j < 4; j++)
        tile[ty + j * 8][tx] = Wb[(size_t)(k0 + ty + j * 8) * N + n0 + tx];
    __syncthreads();
    #pragma unroll
    for (int j = 0; j < 4; j++) {
        const int n = ty + j * 8;
        Wtb[(size_t)(n0 + n) * K + k0 + tx] = (short)bfbits(tile[tx][n]);
    }
}

// ---------------------------------------------------------------------------
// Split-K bf16 MFMA GEMM, double-buffered LDS + register prefetch.
// part[z][M][N] (fp32) = A[:, z*Ksl:(z+1)*Ksl] @ Wt^T slice.
// Grid (N/64, M/64, KS). 256 thr = 4 waves as 2x2 of 32x32.
// C/D mapping: col=lane&15, row=(lane>>4)*4+r.
// ---------------------------------------------------------------------------
__global__ __launch_bounds__(256, 4)
void gemm_mfma_sk(const float* __restrict__ A, int lda,
                  const short* __restrict__ Wt, int ldw,
                  float* __restrict__ part, int Ncols, size_t strideZ,
                  int Ksl)
{
    constexpr int BM = 64, BN = 64;
    constexpr int FM = 2, FN = 2;
    __shared__ short As[2][BM][40];
    __shared__ short Bs[2][BN][40];
    const int tid = threadIdx.x;
    const int wave = tid >> 6, lane = tid & 63;
    const int lr = lane & 15, lg = lane >> 4;
    const int wm0 = (wave >> 1) * 32, wn0 = (wave & 1) * 32;
    const int bm = blockIdx.y * BM, bn = blockIdx.x * BN;
    const int kbase = blockIdx.z * Ksl;

    f32x4 acc[FM][FN];
    #pragma unroll
    for (int fi = 0; fi < FM; fi++)
        #pragma unroll
        for (int fj = 0; fj < FN; fj++)
            acc[fi][fj] = (f32x4){0.f, 0.f, 0.f, 0.f};

    float4 ar0, ar1; uint4 br0;
    const int arow0 = tid >> 3, aseg0 = tid & 7;          // +256: row+32
    const int brow  = tid >> 2, bseg  = tid & 3;

    auto loadT = [&](int k0) {
        ar0 = *reinterpret_cast<const float4*>(A + (size_t)(bm + arow0) * lda + k0 + aseg0 * 4);
        ar1 = *reinterpret_cast<const float4*>(A + (size_t)(bm + arow0 + 32) * lda + k0 + aseg0 * 4);
        br0 = *reinterpret_cast<const uint4*>(Wt + (size_t)(bn + brow) * ldw + k0 + bseg * 8);
    };
    auto storeT = [&](int buf) {
        uint2 p;
        p.x = (uint)bfbits(ar0.x) | ((uint)bfbits(ar0.y) << 16);
        p.y = (uint)bfbits(ar0.z) | ((uint)bfbits(ar0.w) << 16);
        *reinterpret_cast<uint2*>(&As[buf][arow0][aseg0 * 4]) = p;
        p.x = (uint)bfbits(ar1.x) | ((uint)bfbits(ar1.y) << 16);
        p.y = (uint)bfbits(ar1.z) | ((uint)bfbits(ar1.w) << 16);
        *reinterpret_cast<uint2*>(&As[buf][arow0 + 32][aseg0 * 4]) = p;
        *reinterpret_cast<uint4*>(&Bs[buf][brow][bseg * 8]) = br0;
    };

    loadT(kbase);
    storeT(0);
    const int NK = Ksl >> 5;
    for (int kk = 0; kk < NK; kk++) {
        const int cur = kk & 1;
        if (kk + 1 < NK) loadT(kbase + (kk + 1) * 32);
        __syncthreads();
        bf16x8 af[FM], bfr[FN];
        #pragma unroll
        for (int fi = 0; fi < FM; fi++)
            af[fi] = *reinterpret_cast<const bf16x8*>(&As[cur][wm0 + fi * 16 + lr][lg * 8]);
        #pragma unroll
        for (int fj = 0; fj < FN; fj++)
            bfr[fj] = *reinterpret_cast<const bf16x8*>(&Bs[cur][wn0 + fj * 16 + lr][lg * 8]);
        #pragma unroll
        for (int fi = 0; fi < FM; fi++)
            #pragma unroll
            for (int fj = 0; fj < FN; fj++)
                acc[fi][fj] = __builtin_amdgcn_mfma_f32_16x16x32_bf16(
                    af[fi], bfr[fj], acc[fi][fj], 0, 0, 0);
        if (kk + 1 < NK) storeT(cur ^ 1);
    }

    float* P = part + (size_t)blockIdx.z * strideZ;
    #pragma unroll
    for (int fi = 0; fi < FM; fi++)
        #pragma unroll
        for (int fj = 0; fj < FN; fj++)
            #pragma unroll
            for (int r = 0; r < 4; r++) {
                const int m = bm + wm0 + fi * 16 + lg * 4 + r;
                const int n = bn + wn0 + fj * 16 + lr;
                P[(size_t)m * Ncols + n] = acc[fi][fj][r];
            }
}

// ---------------------------------------------------------------------------
// Direct-output bf16 MFMA GEMM (W_in), same pipeline, EP=0 epilogue.
// ---------------------------------------------------------------------------
__global__ __launch_bounds__(256, 4)
void gemm_mfma_db(const float* __restrict__ A, int lda,
                  const short* __restrict__ Wt, int ldw,
                  float* __restrict__ C, int ldc, int Kd)
{
    constexpr int BM = 64, BN = 64;
    constexpr int FM = 2, FN = 2;
    __shared__ short As[2][BM][40];
    __shared__ short Bs[2][BN][40];
    const int tid = threadIdx.x;
    const int wave = tid >> 6, lane = tid & 63;
    const int lr = lane & 15, lg = lane >> 4;
    const int wm0 = (wave >> 1) * 32, wn0 = (wave & 1) * 32;
    const int bm = blockIdx.y * BM, bn = blockIdx.x * BN;

    f32x4 acc[FM][FN];
    #pragma unroll
    for (int fi = 0; fi < FM; fi++)
        #pragma unroll
        for (int fj = 0; fj < FN; fj++)
            acc[fi][fj] = (f32x4){0.f, 0.f, 0.f, 0.f};

    float4 ar0, ar1; uint4 br0;
    const int arow0 = tid >> 3, aseg0 = tid & 7;
    const int brow  = tid >> 2, bseg  = tid & 3;

    auto loadT = [&](int k0) {
        ar0 = *reinterpret_cast<const float4*>(A + (size_t)(bm + arow0) * lda + k0 + aseg0 * 4);
        ar1 = *reinterpret_cast<const float4*>(A + (size_t)(bm + arow0 + 32) * lda + k0 + aseg0 * 4);
        br0 = *reinterpret_cast<const uint4*>(Wt + (size_t)(bn + brow) * ldw + k0 + bseg * 8);
    };
    auto storeT = [&](int buf) {
        uint2 p;
        p.x = (uint)bfbits(ar0.x) | ((uint)bfbits(ar0.y) << 16);
        p.y = (uint)bfbits(ar0.z) | ((uint)bfbits(ar0.w) << 16);
        *reinterpret_cast<uint2*>(&As[buf][arow0][aseg0 * 4]) = p;
        p.x = (uint)bfbits(ar1.x) | ((uint)bfbits(ar1.y) << 16);
        p.y = (uint)bfbits(ar1.z) | ((uint)bfbits(ar1.w) << 16);
        *reinterpret_cast<uint2*>(&As[buf][arow0 + 32][aseg0 * 4]) = p;
        *reinterpret_cast<uint4*>(&Bs[buf][brow][bseg * 8]) = br0;
    };

    loadT(0);
    storeT(0);
    const int NK = Kd >> 5;
    for (int kk = 0; kk < NK; kk++) {
        const int cur = kk & 1;
        if (kk + 1 < NK) loadT((kk + 1) * 32);
        __syncthreads();
        bf16x8 af[FM], bfr[FN];
        #pragma unroll
        for (int fi = 0; fi < FM; fi++)
            af[fi] = *reinterpret_cast<const bf16x8*>(&As[cur][wm0 + fi * 16 + lr][lg * 8]);
        #pragma unroll
        for (int fj = 0; fj < FN; fj++)
            bfr[fj] = *reinterpret_cast<const bf16x8*>(&Bs[cur][wn0 + fj * 16 + lr][lg * 8]);
        #pragma unroll
        for (int fi = 0; fi < FM; fi++)
            #pragma unroll
            for (int fj = 0; fj < FN; fj++)
                acc[fi][fj] = __builtin_amdgcn_mfma_f32_16x16x32_bf16(
                    af[fi], bfr[fj], acc[fi][fj], 0, 0, 0);
        if (kk + 1 < NK) storeT(cur ^ 1);
    }

    #pragma unroll
    for (int fi = 0; fi < FM; fi++)
        #pragma unroll
        for (int fj = 0; fj < FN; fj++)
            #pragma unroll
            for (int r = 0; r < 4; r++) {
                const int m = bm + wm0 + fi * 16 + lg * 4 + r;
                const int n = bn + wn0 + fj * 16 + lr;
                C[(size_t)m * ldc + n] = acc[fi][fj][r];
            }
}

// ---------------------------------------------------------------------------
// Split-K reduce + epilogue. idx over M*N/4 (float4).
// EP=1: + e1[n] + e2[act[m]*DM+n]   EP=3: C += sum (residual, in-place)
// ---------------------------------------------------------------------------
template<int EP>
__global__ __launch_bounds__(256)
void gemm_reduce(const float* __restrict__ part, float* __restrict__ C,
                 int MN, const float* __restrict__ e1,
                 const float* __restrict__ e2, const int* __restrict__ act)
{
    const int idx = blockIdx.x * 256 + threadIdx.x;
    const size_t off = (size_t)idx * 4;
    float4 s = {0.f, 0.f, 0.f, 0.f};
    #pragma unroll
    for (int z = 0; z < GKS; z++) {
        const float4 p = *reinterpret_cast<const float4*>(part + (size_t)z * MN + off);
        s.x += p.x; s.y += p.y; s.z += p.z; s.w += p.w;
    }
    if (EP == 1) {
        const int m = (int)(off >> 9);           // N = 512
        const int n0 = (int)(off & 511);
        const float* e2r = e2 + (size_t)act[m] * DM;
        s.x += e1[n0]     + e2r[n0];
        s.y += e1[n0 + 1] + e2r[n0 + 1];
        s.z += e1[n0 + 2] + e2r[n0 + 2];
        s.w += e1[n0 + 3] + e2r[n0 + 3];
    }
    if (EP == 3) {
        const float4 c0 = *reinterpret_cast<const float4*>(C + off);
        s.x += c0.x; s.y += c0.y; s.z += c0.z; s.w += c0.w;
    }
    *reinterpret_cast<float4*>(C + off) = s;
}

// ---------------------------------------------------------------------------
// fp32 tiled GEMM (dt: K=32). EP=2: softplus(c + e1[n])
// ---------------------------------------------------------------------------
template<int EP>
__global__ __launch_bounds__(256)
void gemm64(const float* __restrict__ A, int lda,
            const float* __restrict__ Bw, int ldb,
            float* __restrict__ C, int ldc, int Kd,
            const float* __restrict__ e1)
{
    __shared__ float As[16][68];
    __shared__ float Bs[16][68];
    const int tx = threadIdx.x, ty = threadIdx.y;
    const int tid = ty * 16 + tx;
    const int bm = blockIdx.y * 64, bn = blockIdx.x * 64;
    float c[4][4] = {};
    for (int k0 = 0; k0 < Kd; k0 += 16) {
        #pragma unroll
        for (int j = 0; j < 4; j++) {
            int idx = tid + 256 * j;
            int kk = idx & 15, ml = idx >> 4;
            As[kk][ml] = A[(size_t)(bm + ml) * lda + k0 + kk];
        }
        #pragma unroll
        for (int j = 0; j < 4; j++) {
            int idx = tid + 256 * j;
            int nl = idx & 63, kk = idx >> 6;
            Bs[kk][nl] = Bw[(size_t)(k0 + kk) * ldb + bn + nl];
        }
        __syncthreads();
        #pragma unroll
        for (int kk = 0; kk < 16; kk++) {
            float a[4], b[4];
            #pragma unroll
            for (int i = 0; i < 4; i++) a[i] = As[kk][ty * 4 + i];
            #pragma unroll
            for (int i = 0; i < 4; i++) b[i] = Bs[kk][tx * 4 + i];
            #pragma unroll
            for (int i = 0; i < 4; i++)
                #pragma unroll
                for (int j = 0; j < 4; j++)
                    c[i][j] += a[i] * b[j];
        }
        __syncthreads();
    }
    #pragma unroll
    for (int i = 0; i < 4; i++) {
        int m = bm + ty * 4 + i;
        #pragma unroll
        for (int j = 0; j < 4; j++) {
            int n = bn + tx * 4 + j;
            float v = c[i][j];
            if (EP == 2) { v += e1[n]; v = fmaxf(v, 0.f) + log1pf(expf(-fabsf(v))); }
            C[(size_t)m * ldc + n] = v;
        }
    }
}

// ---------------------------------------------------------------------------
// xproj split-K + reduce
// ---------------------------------------------------------------------------
__global__ __launch_bounds__(256)
void gemm_xproj(const float* __restrict__ A, const float* __restrict__ W,
                float* __restrict__ part)
{
    __shared__ float As[16][68];
    __shared__ float Bs[16][68];
    const int tx = threadIdx.x, ty = threadIdx.y;
    const int tid = ty * 16 + tx;
    const int sk = blockIdx.x;
    const int bm = blockIdx.y * 64;
    float c[4][4] = {};
    for (int k0 = sk * 64; k0 < sk * 64 + 64; k0 += 16) {
        #pragma unroll
        for (int j = 0; j < 4; j++) {
            int idx = tid + 256 * j;
            int kk = idx & 15, ml = idx >> 4;
            As[kk][ml] = A[(size_t)(bm + ml) * DI + k0 + kk];
        }
        #pragma unroll
        for (int j = 0; j < 4; j++) {
            int idx = tid + 256 * j;
            int nl = idx & 63, kk = idx >> 6;
            Bs[kk][nl] = W[(size_t)(k0 + kk) * 64 + nl];
        }
        __syncthreads();
        #pragma unroll
        for (int kk = 0; kk < 16; kk++) {
            float a[4], b[4];
            #pragma unroll
            for (int i = 0; i < 4; i++) a[i] = As[kk][ty * 4 + i];
            #pragma unroll
            for (int i = 0; i < 4; i++) b[i] = Bs[kk][tx * 4 + i];
            #pragma unroll
            for (int i = 0; i < 4; i++)
                #pragma unroll
                for (int j = 0; j < 4; j++)
                    c[i][j] += a[i] * b[j];
        }
        __syncthreads();
    }
    float* Cp = part + ((size_t)sk * BT + bm) * 64;
    #pragma unroll
    for (int i = 0; i < 4; i++)
        #pragma unroll
        for (int j = 0; j < 4; j++)
            Cp[(size_t)(ty * 4 + i) * 64 + tx * 4 + j] = c[i][j];
}

__global__ __launch_bounds__(256)
void xproj_reduce(const float* __restrict__ part, float* __restrict__ dbc)
{
    const int idx = blockIdx.x * 256 + threadIdx.x;   // BT*64
    float s = 0.f;
    #pragma unroll
    for (int sk = 0; sk < SK; sk++) s += part[(size_t)sk * BT * 64 + idx];
    dbc[idx] = s;
}

// ---------------------------------------------------------------------------
// LayerNorm over rows of length DM.
// ---------------------------------------------------------------------------
__global__ __launch_bounds__(256)
void ln_kernel(const float* __restrict__ x, const float* __restrict__ w,
               const float* __restrict__ bb, float* __restrict__ o)
{
    const int row = blockIdx.x;
    const int tid = threadIdx.x;
    const float* xr = x + (size_t)row * DM;
    float s = 0.f, ss = 0.f;
    for (int i = tid; i < DM; i += 256) { float v = xr[i]; s += v; ss += v * v; }
    #pragma unroll
    for (int m = 32; m >= 1; m >>= 1) { s += __shfl_xor(s, m, 64); ss += __shfl_xor(ss, m, 64); }
    __shared__ float sm[4], sm2[4];
    const int wv = tid >> 6;
    if ((tid & 63) == 0) { sm[wv] = s; sm2[wv] = ss; }
    __syncthreads();
    s  = sm[0] + sm[1] + sm[2] + sm[3];
    ss = sm2[0] + sm2[1] + sm2[2] + sm2[3];
    const float mean = s * (1.f / DM);
    float var = ss * (1.f / DM) - mean * mean;
    var = fmaxf(var, 0.f);
    const float rstd = rsqrtf(var + EPSV);
    for (int i = tid; i < DM; i += 256) {
        float v = (xr[i] - mean) * rstd;
        o[(size_t)row * DM + i] = v * w[i] + bb[i];
    }
}

// ---------------------------------------------------------------------------
// Causal depthwise conv (K=4) + SiLU.
// ---------------------------------------------------------------------------
__global__ __launch_bounds__(256)
void conv_silu(const float* __restrict__ xz, const float* __restrict__ cw,
               const float* __restrict__ cb, float* __restrict__ xc)
{
    const int idx = blockIdx.x * 256 + threadIdx.x;   // over BT*DI
    const int d = idx & (DI - 1);
    const int bt = idx >> 10;
    const int t = bt & (T_ - 1);
    float acc = cb[d];
    #pragma unroll
    for (int k = 0; k < KC; k++) {
        int sh = 3 - k;
        if (t >= sh) acc += cw[d * KC + k] * xz[(size_t)(bt - sh) * 2048 + d];
    }
    const float sg = 1.f / (1.f + __expf(-acc));
    xc[idx] = acc * sg;
}

// ---------------------------------------------------------------------------
// Scan pass A: one thread per (b,chunk,d); all 16 states in registers.
// ---------------------------------------------------------------------------
__global__ __launch_bounds__(256)
void scan_passA(const float* __restrict__ dt, const float* __restrict__ xc,
                const float* __restrict__ dbc, const float* __restrict__ A_log,
                float* __restrict__ Aprod, float* __restrict__ hloc)
{
    const int blk = blockIdx.x;
    const int dg = blk & 3;
    const int c  = (blk >> 2) & (CH - 1);
    const int b  = blk >> 7;
    const int d  = dg * 256 + threadIdx.x;
    const size_t base = (size_t)b * T_ + c * TC;

    __shared__ float Bsh[TC][DS];
    {
        const int i = threadIdx.x;   // TC*DS = 256
        const int t = i >> 4, s = i & 15;
        Bsh[t][s] = dbc[(base + t) * 64 + 32 + s];
    }
    __syncthreads();

    float Aval[DS], h[DS], ap[DS];
    #pragma unroll
    for (int s = 0; s < DS; s++) {
        Aval[s] = -__expf(A_log[(size_t)d * DS + s]);
        h[s] = 0.f; ap[s] = 1.f;
    }

    #pragma unroll 4
    for (int t = 0; t < TC; t++) {
        const size_t r = base + t;
        const float dtv = dt[r * DI + d];
        const float xv  = xc[r * DI + d];
        const float u = dtv * xv;
        #pragma unroll
        for (int s = 0; s < DS; s++) {
            const float a = __expf(dtv * Aval[s]);
            h[s] = a * h[s] + u * Bsh[t][s];
            ap[s] *= a;
        }
    }
    const size_t o0 = ((size_t)(b * CH + c) * DS) * DI + d;
    #pragma unroll
    for (int s = 0; s < DS; s++) {
        Aprod[o0 + (size_t)s * DI] = ap[s];
        hloc[o0 + (size_t)s * DI]  = h[s];
    }
}

// ---------------------------------------------------------------------------
// Scan pass B: fold chunk summaries in-place (hloc[c] <- h0 of chunk c).
// ---------------------------------------------------------------------------
__global__ __launch_bounds__(256)
void scan_passB(const float* __restrict__ Aprod, float* __restrict__ hloc)
{
    const int idx = blockIdx.x * 256 + threadIdx.x;   // B*DS*DI = 65536
    const int d = idx & (DI - 1);
    const int s = (idx >> 10) & (DS - 1);
    const int b = idx >> 14;
    float h = 0.f;
    for (int c = 0; c < CH; c++) {
        const size_t o = ((size_t)(b * CH + c) * DS + s) * DI + d;
        const float a  = Aprod[o];
        const float hl = hloc[o];
        hloc[o] = h;                 // h0 for chunk c
        h = a * h + hl;
    }
}

// ---------------------------------------------------------------------------
// Scan pass C: loads h0, recomputes chunk, emits gated y.
// ---------------------------------------------------------------------------
__global__ __launch_bounds__(256)
void scan_passC(const float* __restrict__ dt, const float* __restrict__ xc,
                const float* __restrict__ dbc, const float* __restrict__ xz,
                const float* __restrict__ A_log, const float* __restrict__ Dskip,
                const float* __restrict__ h0buf, float* __restrict__ y)
{
    const int blk = blockIdx.x;
    const int dg = blk & 3;
    const int c  = (blk >> 2) & (CH - 1);
    const int b  = blk >> 7;
    const int d  = dg * 256 + threadIdx.x;
    const size_t base = (size_t)b * T_ + c * TC;

    __shared__ float Bsh[TC][DS];
    __shared__ float Csh[TC][DS];
    for (int i = threadIdx.x; i < TC * 32; i += 256) {
        const int t = i >> 5, sc = i & 31;
        const float v = dbc[(base + t) * 64 + 32 + sc];
        if (sc < 16) Bsh[t][sc] = v; else Csh[t][sc - 16] = v;
    }
    __syncthreads();

    float Aval[DS], h[DS];
    const size_t o0 = ((size_t)(b * CH + c) * DS) * DI + d;
    #pragma unroll
    for (int s = 0; s < DS; s++) {
        Aval[s] = -__expf(A_log[(size_t)d * DS + s]);
        h[s] = h0buf[o0 + (size_t)s * DI];
    }
    const float Dv = Dskip[d];

    #pragma unroll 2
    for (int t = 0; t < TC; t++) {
        const size_t r = base + t;
        const float dtv = dt[r * DI + d];
        const float xv  = xc[r * DI + d];
        const float u = dtv * xv;
        float yacc = 0.f;
        #pragma unroll
        for (int s = 0; s < DS; s++) {
            const float a = __expf(dtv * Aval[s]);
            h[s] = a * h[s] + u * Bsh[t][s];
            yacc += h[s] * Csh[t][s];
        }
        const float zv = xz[r * 2048 + 1024 + d];
        const float sg = 1.f / (1.f + __expf(-zv));
        y[r * DI + d] = (yacc + Dv * xv) * (zv * sg);
    }
}

// ---------------------------------------------------------------------------
__global__ __launch_bounds__(256)
void mean_kernel(const float* __restrict__ x, float* __restrict__ out)
{
    const int idx = blockIdx.x * 256 + threadIdx.x;   // B*DM
    const int b = idx / DM;
    const int dcol = idx % DM;
    float ssum = 0.f;
    for (int t = 0; t < T_; t++) ssum += x[((size_t)b * T_ + t) * DM + dcol];
    out[idx] = ssum * (1.f / T_);
}

// ---------------------------------------------------------------------------
extern "C" void kernel_launch(void* const* d_in, const int* in_sizes, int n_in,
                              void* d_out, int out_size, void* d_ws, size_t ws_size,
                              hipStream_t stream)
{
    const float* samples  = (const float*)d_in[0];
    const int*   actions  = (const int*)  d_in[1];
    const float* W_embed  = (const float*)d_in[2];
    const float* b_embed  = (const float*)d_in[3];
    const float* act_emb  = (const float*)d_in[4];
    const float* ln_w     = (const float*)d_in[5];
    const float* ln_b     = (const float*)d_in[6];
    const float* W_in     = (const float*)d_in[7];
    const float* conv_w   = (const float*)d_in[8];
    const float* conv_b   = (const float*)d_in[9];
    const float* W_xproj  = (const float*)d_in[10];
    const float* W_dt     = (const float*)d_in[11];
    const float* b_dt     = (const float*)d_in[12];
    const float* A_log    = (const float*)d_in[13];
    const float* D_skip   = (const float*)d_in[14];
    const float* W_out    = (const float*)d_in[15];
    const float* normf_w  = (const float*)d_in[16];
    const float* normf_b  = (const float*)d_in[17];
    const float* out_ln_w = (const float*)d_in[18];
    const float* out_ln_b = (const float*)d_in[19];

    float* ws  = (float*)d_ws;
    float* x    = ws;                          // BT*DM
    float* h    = x    + (size_t)BT * DM;      // BT*DM
    float* xz   = h    + (size_t)BT * DM;      // BT*2048
    float* xc   = xz   + (size_t)BT * 2048;    // BT*DI
    float* dbc  = xc   + (size_t)BT * DI;      // BT*64
    float* dtb  = dbc  + (size_t)BT * 64;      // BT*DI
    float* yg   = dtb  + (size_t)BT * DI;      // BT*DI
    float* Apr  = yg   + (size_t)BT * DI;      // B*CH*DS*DI (2M floats)
    float* hlo  = Apr  + (size_t)B_ * CH * DI * DS;  // 2M floats
    float* part = Apr;                         // xproj partials alias (2M floats)
    float* gpart = Apr;                        // GEMM split-K partials alias (4M floats = Apr+hlo)
    float* wb   = hlo  + (size_t)B_ * CH * DI * DS;
    short* WtE  = (short*)wb;                        // [DM][STOCH]
    short* WtI  = WtE + (size_t)DM * STOCH;          // 4 x [2048][DM]
    short* WtO  = WtI + (size_t)4 * 2048 * DM;       // 4 x [DM][DI]

    dim3 blk2(16, 16);
    const int MN = BT * DM;                    // 2048*512

    // one-time per call: weights -> bf16, transposed [N][K]
    wconvT<<<dim3(DM / 32, STOCH / 32, 1), dim3(32, 8), 0, stream>>>(W_embed, WtE, STOCH, DM);
    wconvT<<<dim3(2048 / 32, DM / 32, 4), dim3(32, 8), 0, stream>>>(W_in, WtI, DM, 2048);
    wconvT<<<dim3(DM / 32, DI / 32, 4), dim3(32, 8), 0, stream>>>(W_out, WtO, DI, DM);

    // x = samples @ W_embed + b_embed + act_embed[actions]  (split-K=4)
    gemm_mfma_sk<<<dim3(DM / 64, BT / 64, GKS), 256, 0, stream>>>(
        samples, STOCH, WtE, STOCH, gpart, DM, (size_t)MN, STOCH / GKS);
    gemm_reduce<1><<<MN / 1024, 256, 0, stream>>>(
        gpart, x, MN, b_embed, act_emb, actions);

    for (int l = 0; l < NL; l++) {
        ln_kernel<<<BT, 256, 0, stream>>>(x, ln_w + l * DM, ln_b + l * DM, h);
        // xz = h @ W_in[l]  (direct, 1024 blocks)
        gemm_mfma_db<<<dim3(2048 / 64, BT / 64), 256, 0, stream>>>(
            h, DM, WtI + (size_t)l * 2048 * DM, DM, xz, 2048, DM);
        conv_silu<<<(BT * DI) / 256, 256, 0, stream>>>(
            xz, conv_w + (size_t)l * DI * KC, conv_b + (size_t)l * DI, xc);
        gemm_xproj<<<dim3(SK, BT / 64), blk2, 0, stream>>>(
            xc, W_xproj + (size_t)l * DI * 64, part);
        xproj_reduce<<<(BT * 64) / 256, 256, 0, stream>>>(part, dbc);
        gemm64<2><<<dim3(DI / 64, BT / 64), blk2, 0, stream>>>(
            dbc, 64, W_dt + (size_t)l * DTR * DI, DI, dtb, DI, DTR,
            b_dt + (size_t)l * DI);
        scan_passA<<<B_ * CH * (DI / 256), 256, 0, stream>>>(
            dtb, xc, dbc, A_log + (size_t)l * DI * DS, Apr, hlo);
        scan_passB<<<(B_ * DS * DI) / 256, 256, 0, stream>>>(Apr, hlo);
        scan_passC<<<B_ * CH * (DI / 256), 256, 0, stream>>>(
            dtb, xc, dbc, xz, A_log + (size_t)l * DI * DS, D_skip + (size_t)l * DI,
            hlo, yg);
        // x += yg @ W_out[l]  (split-K=4; gpart aliases Apr+hlo, both dead now)
        gemm_mfma_sk<<<dim3(DM / 64, BT / 64, GKS), 256, 0, stream>>>(
            yg, DI, WtO + (size_t)l * DM * DI, DI, gpart, DM, (size_t)MN, DI / GKS);
        gemm_reduce<3><<<MN / 1024, 256, 0, stream>>>(
            gpart, x, MN, nullptr, nullptr, nullptr);
    }

    ln_kernel<<<BT, 256, 0, stream>>>(x, normf_w, normf_b, h);
    ln_kernel<<<BT, 256, 0, stream>>>(h, out_ln_w, out_ln_b, yg);
    mean_kernel<<<(B_ * DM) / 256, 256, 0, stream>>>(yg, (float*)d_out);
}